// Round 3
// baseline (897.437 us; speedup 1.0000x reference)
//
#include <hip/hip_runtime.h>
#include <stdint.h>

typedef unsigned short u16;
typedef unsigned int u32;
typedef __attribute__((ext_vector_type(8))) short short8;
typedef __attribute__((ext_vector_type(4))) float floatx4;

#define BATCH   131072
#define NA      3
#define OBS     30
#define ACTD    9
#define HID     128
#define HEADS   4
#define HD      32
#define MB      16
#define ROWS    (MB*NA)     // 48
#define LDC     136         // padded row stride
#define LDOA    72          // oa input tile stride
#define QSCALE  0.17677669529663687f
#define NTHREADS 512

// prepacked-weight offsets in d_ws, u16 units (fragment = 64 lanes x 8 bf16)
#define OFF_WO    0
#define OFF_WOA   12288
#define OFF_WQ    36864
#define OFF_WK    53248
#define OFF_WV    69632
#define OFF_WC1   86016
#define OFF_WC2   184320
#define PRE_TOTAL 190464

__device__ __forceinline__ u16 f2bf(float f) {          // round-nearest (ties up)
    union { float f; u32 u; } v; v.f = f;
    return (u16)((v.u + 0x8000u) >> 16);
}
__device__ __forceinline__ u32 pk_bf16(float a, float b) {
    union { float f; u32 u; } x, y; x.f = a; y.f = b;
    return ((x.u + 0x8000u) >> 16) | ((y.u + 0x8000u) & 0xffff0000u);
}
__device__ __forceinline__ float lo16f(u32 w) { union { u32 u; float f; } v; v.u = w << 16; return v.f; }
__device__ __forceinline__ float hi16f(u32 w) { union { u32 u; float f; } v; v.u = w & 0xffff0000u; return v.f; }
__device__ __forceinline__ float leaky(float x) { return x >= 0.f ? x : 0.01f * x; }

// ------------- weight prepack: f32 [k][n] -> bf16 MFMA B-fragment order -------------
__global__ void prepack_kernel(const float* __restrict__ Wo,  const float* __restrict__ Woa,
                               const float* __restrict__ Wq,  const float* __restrict__ Wk,
                               const float* __restrict__ Wv,  const float* __restrict__ Wc1,
                               const float* __restrict__ Wc2, u16* __restrict__ out) {
    int i = blockIdx.x * blockDim.x + threadIdx.x;
    if (i >= PRE_TOTAL) return;
    const float* src; int K, KT, perA, base, Nsrc, Nlim; float scl = 1.f;
    if (i < OFF_WOA)      { src = Wo;  K = 30;  KT = 1; perA = 4096;  base = OFF_WO;  Nsrc = 128; Nlim = 128; }
    else if (i < OFF_WQ)  { src = Woa; K = 39;  KT = 2; perA = 8192;  base = OFF_WOA; Nsrc = 128; Nlim = 128; }
    else if (i < OFF_WK)  { src = Wq;  K = 128; KT = 4; perA = 16384; base = OFF_WQ;  Nsrc = 128; Nlim = 128; scl = QSCALE; }
    else if (i < OFF_WV)  { src = Wk;  K = 128; KT = 4; perA = 16384; base = OFF_WK;  Nsrc = 128; Nlim = 128; }
    else if (i < OFF_WC1) { src = Wv;  K = 128; KT = 4; perA = 16384; base = OFF_WV;  Nsrc = 128; Nlim = 128; }
    else if (i < OFF_WC2) { src = Wc1; K = 256; KT = 8; perA = 32768; base = OFF_WC1; Nsrc = 128; Nlim = 128; }
    else                  { src = Wc2; K = 128; KT = 4; perA = 2048;  base = OFF_WC2; Nsrc = 9;   Nlim = 9;   }
    int j = i - base;
    int agent = j / perA;
    int r = j - agent * perA;
    int e = r & 7, lane = (r >> 3) & 63, fk = r >> 9;
    int kt = fk % KT, nt = fk / KT;
    int n = nt * 16 + (lane & 15);
    int k = kt * 32 + (lane >> 4) * 8 + e;
    u16 v = 0;
    if (k < K && n < Nlim) v = f2bf(src[(agent * K + k) * Nsrc + n] * scl);
    out[i] = v;
}

// ---------------- fused forward: 512 threads (8 waves), 3 blocks/CU -> 24 waves/CU ----------------
// Round-0 structure + one-stage-ahead register prefetch of all weight fragments and
// biases: every preV/bias load is issued a full stage before its consuming barrier,
// so the __syncthreads vmcnt drain hides L2 latency under the previous stage's work.
__global__ __launch_bounds__(NTHREADS, 6) void fused_kernel(
    const float* __restrict__ obs, const float* __restrict__ act,
    const float* __restrict__ b_o, const float* __restrict__ b_oa,
    const float* __restrict__ bq,  const float* __restrict__ bk_, const float* __restrict__ bv,
    const float* __restrict__ bc1, const float* __restrict__ bc2,
    const u16* __restrict__ pre, float* __restrict__ out)
{
    __shared__ __align__(16) u16 s_mem[4 * ROWS * LDC];        // 52224 B -> 3 blk/CU
    u16* s_oemb  = s_mem;                    // o_emb (persistent)
    u16* s_oaemb = s_mem + ROWS * LDC;       // oa_emb -> attn_out
    u16* s_bufA  = s_mem + 2 * ROWS * LDC;   // oa-tile -> Q -> V
    u16* s_bufB  = s_mem + 3 * ROWS * LDC;   // K -> h

    const int tid  = threadIdx.x;
    const int wave = tid >> 6, lane = tid & 63;
    const int l15  = lane & 15, quad = lane >> 4;
    const int b0   = blockIdx.x * MB;
    const short8* preV = (const short8*)pre;

    // ================= PREFETCH stage-1 + stage-2 weights/biases (in flight during stage 0) ==========
    short8 w1[3][2][2]; float b1v[3][2];
    int os1[3], ag1[3], nh21[3], ktn1[3];
    #pragma unroll
    for (int j = 0; j < 3; j++) {
        int sj = wave + 8 * j;
        int osel = sj / 12;
        int rem = sj % 12, agent = rem >> 2, nh2 = rem & 3;
        int KTn = osel ? 2 : 1;
        int preBase = osel ? (OFF_WOA / 8 + agent * 1024) : (OFF_WO / 8 + agent * 512);
        const float* bias = osel ? b_oa : b_o;
        os1[j] = osel; ag1[j] = agent; nh21[j] = nh2; ktn1[j] = KTn;
        #pragma unroll
        for (int n2 = 0; n2 < 2; n2++) {
            int nt = nh2 * 2 + n2;
            w1[j][n2][0] = preV[preBase + (nt * KTn + 0) * 64 + lane];
            if (KTn == 2) w1[j][n2][1] = preV[preBase + (nt * KTn + 1) * 64 + lane];
            b1v[j][n2] = bias[agent * HID + nt * 16 + l15];
        }
    }
    short8 w2[8]; float b2v[2];
    {
        int proj = wave >> 2, nh2s = wave & 3;
        int preBase = (proj ? OFF_WK : OFF_WQ) / 8;
        const float* bias = proj ? bk_ : bq;
        float bscl = proj ? 1.f : QSCALE;
        #pragma unroll
        for (int n2 = 0; n2 < 2; n2++) {
            b2v[n2] = bias[(nh2s * 2 + n2) * 16 + l15] * bscl;
            #pragma unroll
            for (int kt = 0; kt < 4; kt++)
                w2[n2 * 4 + kt] = preV[preBase + ((nh2s * 2 + n2) * 4 + kt) * 64 + lane];
        }
    }

    // ---- stage 0: stage [obs|act|0] tile as packed u32 writes, layout [agent][MB][LDOA] ----
    for (int g = tid; g < ROWS * 15; g += NTHREADS) {          // obs k=0..29
        int r = g / 15, s = g - r * 15;
        int n = r / MB, bl = r - n * MB;
        const float* src = &obs[((b0 + bl) * NA + n) * OBS + 2 * s];
        *(u32*)&s_bufA[n * (MB * LDOA) + bl * LDOA + 2 * s] = pk_bf16(src[0], src[1]);
    }
    for (int g = tid; g < ROWS * 5; g += NTHREADS) {           // act k=30..38, zero k=39
        int r = g / 5, s = g - r * 5;
        int n = r / MB, bl = r - n * MB;
        const float* src = &act[((b0 + bl) * NA + n) * ACTD + 2 * s];
        float v0 = src[0], v1 = (s < 4) ? src[1] : 0.f;
        *(u32*)&s_bufA[n * (MB * LDOA) + bl * LDOA + 30 + 2 * s] = pk_bf16(v0, v1);
    }
    for (int g = tid; g < ROWS * 3; g += NTHREADS) {           // zero k=40..63 (uint4)
        int r = g / 3, s = g - r * 3;
        int n = r / MB, bl = r - n * MB;
        *(uint4*)&s_bufA[n * (MB * LDOA) + bl * LDOA + 40 + 8 * s] = make_uint4(0, 0, 0, 0);
    }
    __syncthreads();

    // ================= PREFETCH stage-3b (V) weights (in flight during stage 1) ==========
    short8 w3[4]; float b3v;
    {
        #pragma unroll
        for (int kt = 0; kt < 4; kt++)
            w3[kt] = preV[OFF_WV / 8 + (wave * 4 + kt) * 64 + lane];
        b3v = bv[wave * 16 + l15];
    }

    // ---- stage 1: per-agent embeds, 24 jobs (osel, agent, nh2) over 8 waves ----
    #pragma unroll
    for (int j = 0; j < 3; j++) {
        int osel = os1[j], agent = ag1[j], nh2 = nh21[j], KTn = ktn1[j];
        floatx4 acc[2] = {};
        #pragma unroll
        for (int kt = 0; kt < 2; kt++) {
            if (kt < KTn) {
                short8 a = *(const short8*)&s_bufA[agent * (MB * LDOA) + l15 * LDOA + kt * 32 + quad * 8];
                acc[0] = __builtin_amdgcn_mfma_f32_16x16x32_bf16(a, w1[j][0][kt], acc[0], 0, 0, 0);
                acc[1] = __builtin_amdgcn_mfma_f32_16x16x32_bf16(a, w1[j][1][kt], acc[1], 0, 0, 0);
            }
        }
        u16* dst = osel ? s_oaemb : s_oemb;
        #pragma unroll
        for (int n2 = 0; n2 < 2; n2++) {
            int col = (nh2 * 2 + n2) * 16 + l15;
            float bb = b1v[j][n2];
            #pragma unroll
            for (int rg = 0; rg < 4; rg++) {
                int m = quad * 4 + rg;
                dst[(m * NA + agent) * LDC + col] = f2bf(leaky(acc[n2][rg] + bb));
            }
        }
    }
    __syncthreads();

    // ---- stage 2: Q (scale folded into Wq) and K; exactly 8 jobs (proj, nh2) ----
    {
        int proj = wave >> 2, nh2 = wave & 3;   // w0-3: Q, w4-7: K
        const u16* Abuf = proj ? s_oaemb : s_oemb;
        u16* dst = proj ? s_bufB : s_bufA;
        for (int mt = 0; mt < 3; mt++) {
            short8 xa[4];
            #pragma unroll
            for (int kt = 0; kt < 4; kt++)
                xa[kt] = *(const short8*)&Abuf[(mt * 16 + l15) * LDC + kt * 32 + quad * 8];
            floatx4 acc[2] = {};
            #pragma unroll
            for (int n2 = 0; n2 < 2; n2++)
                #pragma unroll
                for (int kt = 0; kt < 4; kt++)
                    acc[n2] = __builtin_amdgcn_mfma_f32_16x16x32_bf16(xa[kt], w2[n2 * 4 + kt], acc[n2], 0, 0, 0);
            #pragma unroll
            for (int n2 = 0; n2 < 2; n2++) {
                int col = (nh2 * 2 + n2) * 16 + l15;
                float bb = b2v[n2];
                #pragma unroll
                for (int rg = 0; rg < 4; rg++) {
                    int m = mt * 16 + quad * 4 + rg;
                    dst[m * LDC + col] = f2bf(acc[n2][rg] + bb);
                }
            }
        }
    }
    __syncthreads();

    // ================= PREFETCH stage-4 weights/biases (in flight during 3a) ==========
    short8 w4[3][8]; float b4v[3];
    #pragma unroll
    for (int j = 0; j < 3; j++) {          // stage-4 job j: agent=j, nt=wave
        #pragma unroll
        for (int kt = 0; kt < 8; kt++)
            w4[j][kt] = preV[OFF_WC1 / 8 + j * 4096 + (wave * 8 + kt) * 64 + lane];
        b4v[j] = bc1[j * HID + wave * 16 + l15];
    }

    // ---- stage 3a: masked softmax, off-diagonal only; probs stay in registers ----
    float2 prob = make_float2(0.f, 0.f);
    int e3 = 0, h3 = 0, n3 = 0, m30 = 0, m31 = 0;
    const bool attn_thread = (tid < MB * HEADS * NA);
    if (attn_thread) {
        int r = tid;
        e3 = r / (HEADS * NA); r -= e3 * HEADS * NA; h3 = r / NA; n3 = r - h3 * NA;
        m30 = (n3 == 0) ? 1 : 0;
        m31 = (n3 == 2) ? 1 : 2;
        const uint4* qp  = (const uint4*)&s_bufA[(e3 * NA + n3) * LDC + h3 * HD];
        const uint4* kp0 = (const uint4*)&s_bufB[(e3 * NA + m30) * LDC + h3 * HD];
        const uint4* kp1 = (const uint4*)&s_bufB[(e3 * NA + m31) * LDC + h3 * HD];
        float s0 = 0.f, s1 = 0.f;
        #pragma unroll
        for (int c = 0; c < 4; c++) {
            uint4 qw = qp[c], aw = kp0[c], bw = kp1[c];
            u32 qv[4] = {qw.x, qw.y, qw.z, qw.w};
            u32 av[4] = {aw.x, aw.y, aw.z, aw.w};
            u32 bv_[4] = {bw.x, bw.y, bw.z, bw.w};
            #pragma unroll
            for (int j = 0; j < 4; j++) {
                float ql = lo16f(qv[j]), qh = hi16f(qv[j]);
                s0 += ql * lo16f(av[j]) + qh * hi16f(av[j]);
                s1 += ql * lo16f(bv_[j]) + qh * hi16f(bv_[j]);
            }
        }
        float mx = fmaxf(s0, s1);
        float p0 = __expf(s0 - mx), p1 = __expf(s1 - mx);
        float inv = 1.f / (p0 + p1);
        prob = make_float2(p0 * inv, p1 * inv);
    }
    __syncthreads();

    // ---- stage 3b: V = oa_emb @ Wv + bv ; 8 jobs (nt = wave) ----
    {
        int nt = wave;
        for (int mt = 0; mt < 3; mt++) {
            short8 xa[4];
            #pragma unroll
            for (int kt = 0; kt < 4; kt++)
                xa[kt] = *(const short8*)&s_oaemb[(mt * 16 + l15) * LDC + kt * 32 + quad * 8];
            floatx4 acc = {};
            #pragma unroll
            for (int kt = 0; kt < 4; kt++)
                acc = __builtin_amdgcn_mfma_f32_16x16x32_bf16(xa[kt], w3[kt], acc, 0, 0, 0);
            int col = nt * 16 + l15;
            float bb = b3v;
            #pragma unroll
            for (int rg = 0; rg < 4; rg++) {
                int m = mt * 16 + quad * 4 + rg;
                s_bufA[m * LDC + col] = f2bf(acc[rg] + bb);
            }
        }
    }
    __syncthreads();

    // ---- stage 3c: attn_out = probs @ V (probs from registers) ----
    if (attn_thread) {
        const uint4* v0p = (const uint4*)&s_bufA[(e3 * NA + m30) * LDC + h3 * HD];
        const uint4* v1p = (const uint4*)&s_bufA[(e3 * NA + m31) * LDC + h3 * HD];
        uint4* dst = (uint4*)&s_oaemb[(e3 * NA + n3) * LDC + h3 * HD];
        #pragma unroll
        for (int c = 0; c < 4; c++) {
            uint4 aw = v0p[c], bw = v1p[c], ow;
            u32 av[4] = {aw.x, aw.y, aw.z, aw.w};
            u32 bv_[4] = {bw.x, bw.y, bw.z, bw.w};
            u32 ov[4];
            #pragma unroll
            for (int j = 0; j < 4; j++) {
                float lo = prob.x * lo16f(av[j]) + prob.y * lo16f(bv_[j]);
                float hi = prob.x * hi16f(av[j]) + prob.y * hi16f(bv_[j]);
                ov[j] = pk_bf16(lo, hi);
            }
            ow.x = ov[0]; ow.y = ov[1]; ow.z = ov[2]; ow.w = ov[3];
            dst[c] = ow;
        }
    }
    __syncthreads();

    // ================= PREFETCH stage-5 weights/bias (in flight during stage 4) ==========
    short8 w5[4]; float b5v = 0.f;
    if (wave < NA) {
        #pragma unroll
        for (int kt = 0; kt < 4; kt++)
            w5[kt] = preV[OFF_WC2 / 8 + wave * 256 + kt * 64 + lane];
        if (l15 < ACTD) b5v = bc2[wave * ACTD + l15];
    }

    // ---- stage 4: critic layer 1, 24 jobs (agent=j, nt=wave); K-split concat ----
    #pragma unroll
    for (int j = 0; j < 3; j++) {
        int agent = j, nt = wave;
        floatx4 acc = {};
        #pragma unroll
        for (int kt = 0; kt < 8; kt++) {
            const u16* A = (kt < 4) ? s_oemb : s_oaemb;
            int kk = (kt & 3) * 32 + quad * 8;
            short8 a = *(const short8*)&A[(l15 * NA + agent) * LDC + kk];
            acc = __builtin_amdgcn_mfma_f32_16x16x32_bf16(a, w4[j][kt], acc, 0, 0, 0);
        }
        int col = nt * 16 + l15;
        float bb = b4v[j];
        #pragma unroll
        for (int rg = 0; rg < 4; rg++) {
            int m = quad * 4 + rg;
            s_bufB[(m * NA + agent) * LDC + col] = f2bf(leaky(acc[rg] + bb));
        }
    }
    __syncthreads();

    // ---- stage 5: critic layer 2 -> q_values, f32 out ----
    if (wave < NA) {
        int agent = wave;
        floatx4 acc = {};
        #pragma unroll
        for (int kt = 0; kt < 4; kt++) {
            short8 a = *(const short8*)&s_bufB[(l15 * NA + agent) * LDC + kt * 32 + quad * 8];
            acc = __builtin_amdgcn_mfma_f32_16x16x32_bf16(a, w5[kt], acc, 0, 0, 0);
        }
        int col = l15;
        if (col < ACTD) {
            #pragma unroll
            for (int rg = 0; rg < 4; rg++) {
                int m = quad * 4 + rg;
                out[((b0 + m) * NA + agent) * ACTD + col] = acc[rg] + b5v;
            }
        }
    }
}

extern "C" void kernel_launch(void* const* d_in, const int* in_sizes, int n_in,
                              void* d_out, int out_size, void* d_ws, size_t ws_size,
                              hipStream_t stream) {
    const float* obs = (const float*)d_in[0];
    const float* act = (const float*)d_in[1];
    const float* Wo  = (const float*)d_in[2];
    const float* bo  = (const float*)d_in[3];
    const float* Woa = (const float*)d_in[4];
    const float* boa = (const float*)d_in[5];
    const float* Wq  = (const float*)d_in[6];
    const float* bq  = (const float*)d_in[7];
    const float* Wk  = (const float*)d_in[8];
    const float* bk  = (const float*)d_in[9];
    const float* Wv  = (const float*)d_in[10];
    const float* bv  = (const float*)d_in[11];
    const float* Wc1 = (const float*)d_in[12];
    const float* bc1 = (const float*)d_in[13];
    const float* Wc2 = (const float*)d_in[14];
    const float* bc2 = (const float*)d_in[15];
    u16* pre = (u16*)d_ws;   // needs 380928 B of workspace

    prepack_kernel<<<(PRE_TOTAL + 255) / 256, 256, 0, stream>>>(Wo, Woa, Wq, Wk, Wv, Wc1, Wc2, pre);
    fused_kernel<<<BATCH / MB, NTHREADS, 0, stream>>>(obs, act, bo, boa, bq, bk, bv, bc1, bc2, pre,
                                                      (float*)d_out);
}

// Round 4
// 872.977 us; speedup vs baseline: 1.0280x; 1.0280x over previous
//
#include <hip/hip_runtime.h>
#include <stdint.h>

typedef unsigned short u16;
typedef unsigned int u32;
typedef __attribute__((ext_vector_type(8))) short short8;
typedef __attribute__((ext_vector_type(4))) float floatx4;

#define BATCH   131072
#define NA      3
#define OBS     30
#define ACTD    9
#define HID     128
#define HEADS   4
#define HD      32
#define MB      16
#define ROWS    (MB*NA)     // 48
#define LDC     136         // padded row stride
#define LDOA    72          // oa input tile stride
#define QSCALE  0.17677669529663687f
#define NTHREADS 512

// prepacked-weight offsets in d_ws, u16 units (fragment = 64 lanes x 8 bf16)
#define OFF_WO    0
#define OFF_WOA   12288
#define OFF_WQ    36864
#define OFF_WK    53248
#define OFF_WV    69632
#define OFF_WC1   86016
#define OFF_WC2   184320
#define PRE_TOTAL 190464

#define MFMA(A,B,C) __builtin_amdgcn_mfma_f32_16x16x32_bf16((A),(B),(C),0,0,0)

__device__ __forceinline__ u16 f2bf(float f) {          // round-nearest (ties up)
    union { float f; u32 u; } v; v.f = f;
    return (u16)((v.u + 0x8000u) >> 16);
}
__device__ __forceinline__ u32 pk_bf16(float a, float b) {
    union { float f; u32 u; } x, y; x.f = a; y.f = b;
    return ((x.u + 0x8000u) >> 16) | ((y.u + 0x8000u) & 0xffff0000u);
}
__device__ __forceinline__ float lo16f(u32 w) { union { u32 u; float f; } v; v.u = w << 16; return v.f; }
__device__ __forceinline__ float hi16f(u32 w) { union { u32 u; float f; } v; v.u = w & 0xffff0000u; return v.f; }
__device__ __forceinline__ float leaky(float x) { return x >= 0.f ? x : 0.01f * x; }

// ------------- weight prepack: f32 [k][n] -> bf16 MFMA B-fragment order -------------
__global__ void prepack_kernel(const float* __restrict__ Wo,  const float* __restrict__ Woa,
                               const float* __restrict__ Wq,  const float* __restrict__ Wk,
                               const float* __restrict__ Wv,  const float* __restrict__ Wc1,
                               const float* __restrict__ Wc2, u16* __restrict__ out) {
    int i = blockIdx.x * blockDim.x + threadIdx.x;
    if (i >= PRE_TOTAL) return;
    const float* src; int K, KT, perA, base, Nsrc, Nlim; float scl = 1.f;
    if (i < OFF_WOA)      { src = Wo;  K = 30;  KT = 1; perA = 4096;  base = OFF_WO;  Nsrc = 128; Nlim = 128; }
    else if (i < OFF_WQ)  { src = Woa; K = 39;  KT = 2; perA = 8192;  base = OFF_WOA; Nsrc = 128; Nlim = 128; }
    else if (i < OFF_WK)  { src = Wq;  K = 128; KT = 4; perA = 16384; base = OFF_WQ;  Nsrc = 128; Nlim = 128; scl = QSCALE; }
    else if (i < OFF_WV)  { src = Wk;  K = 128; KT = 4; perA = 16384; base = OFF_WK;  Nsrc = 128; Nlim = 128; }
    else if (i < OFF_WC1) { src = Wv;  K = 128; KT = 4; perA = 16384; base = OFF_WV;  Nsrc = 128; Nlim = 128; }
    else if (i < OFF_WC2) { src = Wc1; K = 256; KT = 8; perA = 32768; base = OFF_WC1; Nsrc = 128; Nlim = 128; }
    else                  { src = Wc2; K = 128; KT = 4; perA = 2048;  base = OFF_WC2; Nsrc = 9;   Nlim = 9;   }
    int j = i - base;
    int agent = j / perA;
    int r = j - agent * perA;
    int e = r & 7, lane = (r >> 3) & 63, fk = r >> 9;
    int kt = fk % KT, nt = fk / KT;
    int n = nt * 16 + (lane & 15);
    int k = kt * 32 + (lane >> 4) * 8 + e;
    u16 v = 0;
    if (k < K && n < Nlim) v = f2bf(src[(agent * K + k) * Nsrc + n] * scl);
    out[i] = v;
}

// ---------------- fused forward: 512 threads (8 waves), 3 blocks/CU -> 24 waves/CU ----------------
// Round-0 structure + one-barrier-ahead register prefetch of all weight fragments and
// biases, held in NAMED scalar registers only (no arrays -> no scratch; rule #20).
// Each __syncthreads' vmcnt(0) drain completes the next stage's weights under the
// current stage's compute.
__global__ __launch_bounds__(NTHREADS, 6) void fused_kernel(
    const float* __restrict__ obs, const float* __restrict__ act,
    const float* __restrict__ b_o, const float* __restrict__ b_oa,
    const float* __restrict__ bq,  const float* __restrict__ bk_, const float* __restrict__ bv,
    const float* __restrict__ bc1, const float* __restrict__ bc2,
    const u16* __restrict__ pre, float* __restrict__ out)
{
    __shared__ __align__(16) u16 s_mem[4 * ROWS * LDC];        // 52224 B -> 3 blk/CU
    u16* s_oemb  = s_mem;                    // o_emb (persistent)
    u16* s_oaemb = s_mem + ROWS * LDC;       // oa_emb -> attn_out
    u16* s_bufA  = s_mem + 2 * ROWS * LDC;   // oa-tile -> Q -> V
    u16* s_bufB  = s_mem + 3 * ROWS * LDC;   // K -> h

    const int tid  = threadIdx.x;
    const int wave = tid >> 6, lane = tid & 63;
    const int l15  = lane & 15, quad = lane >> 4;
    const int b0   = blockIdx.x * MB;
    const short8* preV = (const short8*)pre;

    const int nh2 = wave & 3;                // shared n-tile-pair index for stage-1 jobs & stage 2

    // ============ PREFETCH stage-1 weights/biases (drain under stage 0) ============
    // job0: osel=0, KTn=1, agent=wave>>2       (waves 0-7)
    // job1: wave<4: osel=0,KTn=1,agent=2 ; wave>=4: osel=1,KTn=2,agent=0
    // job2: osel=1, KTn=2, agent=(wave+4)>>2
    const int ag0 = wave >> 2;
    const int ag2 = (wave + 4) >> 2;
    const int pb0 = OFF_WO / 8 + ag0 * 512;
    const int pb1 = (wave < 4) ? (OFF_WO / 8 + 2 * 512) : (OFF_WOA / 8);
    const int kt1n = (wave < 4) ? 1 : 2;     // job1 KT
    const int pb2 = OFF_WOA / 8 + ag2 * 1024;
    short8 w1_00 = preV[pb0 + (nh2 * 2 + 0) * 64 + lane];
    short8 w1_01 = preV[pb0 + (nh2 * 2 + 1) * 64 + lane];
    short8 w1_100 = preV[pb1 + ((nh2 * 2 + 0) * kt1n + 0) * 64 + lane];
    short8 w1_101 = preV[pb1 + ((nh2 * 2 + 0) * kt1n + 1) * 64 + lane];   // unused if kt1n==1 (valid mem)
    short8 w1_110 = preV[pb1 + ((nh2 * 2 + 1) * kt1n + 0) * 64 + lane];
    short8 w1_111 = preV[pb1 + ((nh2 * 2 + 1) * kt1n + 1) * 64 + lane];
    short8 w1_200 = preV[pb2 + ((nh2 * 2 + 0) * 2 + 0) * 64 + lane];
    short8 w1_201 = preV[pb2 + ((nh2 * 2 + 0) * 2 + 1) * 64 + lane];
    short8 w1_210 = preV[pb2 + ((nh2 * 2 + 1) * 2 + 0) * 64 + lane];
    short8 w1_211 = preV[pb2 + ((nh2 * 2 + 1) * 2 + 1) * 64 + lane];
    const float* bj0 = b_o + ag0 * HID;
    const float* bj1 = (wave < 4) ? (b_o + 2 * HID) : b_oa;
    const float* bj2 = b_oa + ag2 * HID;
    float b1_00 = bj0[(nh2 * 2 + 0) * 16 + l15];
    float b1_01 = bj0[(nh2 * 2 + 1) * 16 + l15];
    float b1_10 = bj1[(nh2 * 2 + 0) * 16 + l15];
    float b1_11 = bj1[(nh2 * 2 + 1) * 16 + l15];
    float b1_20 = bj2[(nh2 * 2 + 0) * 16 + l15];
    float b1_21 = bj2[(nh2 * 2 + 1) * 16 + l15];

    // ============ PREFETCH stage-2 weights/biases (drain under stage 0/1) ============
    const int proj = wave >> 2;              // w0-3: Q, w4-7: K
    const int pbqk = (proj ? OFF_WK : OFF_WQ) / 8;
    const float* bqk = proj ? bk_ : bq;
    const float bscl = proj ? 1.f : QSCALE;
    short8 w2_00 = preV[pbqk + ((nh2 * 2 + 0) * 4 + 0) * 64 + lane];
    short8 w2_01 = preV[pbqk + ((nh2 * 2 + 0) * 4 + 1) * 64 + lane];
    short8 w2_02 = preV[pbqk + ((nh2 * 2 + 0) * 4 + 2) * 64 + lane];
    short8 w2_03 = preV[pbqk + ((nh2 * 2 + 0) * 4 + 3) * 64 + lane];
    short8 w2_10 = preV[pbqk + ((nh2 * 2 + 1) * 4 + 0) * 64 + lane];
    short8 w2_11 = preV[pbqk + ((nh2 * 2 + 1) * 4 + 1) * 64 + lane];
    short8 w2_12 = preV[pbqk + ((nh2 * 2 + 1) * 4 + 2) * 64 + lane];
    short8 w2_13 = preV[pbqk + ((nh2 * 2 + 1) * 4 + 3) * 64 + lane];
    float b2_0 = bqk[(nh2 * 2 + 0) * 16 + l15] * bscl;
    float b2_1 = bqk[(nh2 * 2 + 1) * 16 + l15] * bscl;

    // ---- stage 0: stage [obs|act|0] tile as packed u32 writes, layout [agent][MB][LDOA] ----
    for (int g = tid; g < ROWS * 15; g += NTHREADS) {          // obs k=0..29
        int r = g / 15, s = g - r * 15;
        int n = r / MB, bl = r - n * MB;
        const float* src = &obs[((b0 + bl) * NA + n) * OBS + 2 * s];
        *(u32*)&s_bufA[n * (MB * LDOA) + bl * LDOA + 2 * s] = pk_bf16(src[0], src[1]);
    }
    for (int g = tid; g < ROWS * 5; g += NTHREADS) {           // act k=30..38, zero k=39
        int r = g / 5, s = g - r * 5;
        int n = r / MB, bl = r - n * MB;
        const float* src = &act[((b0 + bl) * NA + n) * ACTD + 2 * s];
        float v0 = src[0], v1 = (s < 4) ? src[1] : 0.f;
        *(u32*)&s_bufA[n * (MB * LDOA) + bl * LDOA + 30 + 2 * s] = pk_bf16(v0, v1);
    }
    for (int g = tid; g < ROWS * 3; g += NTHREADS) {           // zero k=40..63 (uint4)
        int r = g / 3, s = g - r * 3;
        int n = r / MB, bl = r - n * MB;
        *(uint4*)&s_bufA[n * (MB * LDOA) + bl * LDOA + 40 + 8 * s] = make_uint4(0, 0, 0, 0);
    }
    __syncthreads();

    // ============ PREFETCH stage-3b (V) weights (drain under stage 1) ============
    short8 w3_0 = preV[OFF_WV / 8 + (wave * 4 + 0) * 64 + lane];
    short8 w3_1 = preV[OFF_WV / 8 + (wave * 4 + 1) * 64 + lane];
    short8 w3_2 = preV[OFF_WV / 8 + (wave * 4 + 2) * 64 + lane];
    short8 w3_3 = preV[OFF_WV / 8 + (wave * 4 + 3) * 64 + lane];
    float b3v = bv[wave * 16 + l15];

    // ---- stage 1: per-agent embeds, 3 jobs/wave, named fragments ----
    {
        // job0: agent=ag0, KT=1, dst=s_oemb
        short8 a = *(const short8*)&s_bufA[ag0 * (MB * LDOA) + l15 * LDOA + quad * 8];
        floatx4 acc0 = {}, acc1 = {};
        acc0 = MFMA(a, w1_00, acc0);
        acc1 = MFMA(a, w1_01, acc1);
        int col0 = nh2 * 32 + l15;
        #pragma unroll
        for (int rg = 0; rg < 4; rg++) {
            int m = quad * 4 + rg;
            s_oemb[(m * NA + ag0) * LDC + col0]      = f2bf(leaky(acc0[rg] + b1_00));
            s_oemb[(m * NA + ag0) * LDC + col0 + 16] = f2bf(leaky(acc1[rg] + b1_01));
        }
    }
    {
        // job1: wave<4 -> (o_emb, agent2); wave>=4 -> (oa_emb, agent0)
        int ag1 = (wave < 4) ? 2 : 0;
        short8 a0 = *(const short8*)&s_bufA[ag1 * (MB * LDOA) + l15 * LDOA + quad * 8];
        floatx4 acc0 = {}, acc1 = {};
        acc0 = MFMA(a0, w1_100, acc0);
        acc1 = MFMA(a0, w1_110, acc1);
        if (wave >= 4) {                      // wave-uniform branch
            short8 a1 = *(const short8*)&s_bufA[ag1 * (MB * LDOA) + l15 * LDOA + 32 + quad * 8];
            acc0 = MFMA(a1, w1_101, acc0);
            acc1 = MFMA(a1, w1_111, acc1);
        }
        u16* dst = (wave < 4) ? s_oemb : s_oaemb;
        int col0 = nh2 * 32 + l15;
        #pragma unroll
        for (int rg = 0; rg < 4; rg++) {
            int m = quad * 4 + rg;
            dst[(m * NA + ag1) * LDC + col0]      = f2bf(leaky(acc0[rg] + b1_10));
            dst[(m * NA + ag1) * LDC + col0 + 16] = f2bf(leaky(acc1[rg] + b1_11));
        }
    }
    {
        // job2: oa_emb, agent=ag2, KT=2
        short8 a0 = *(const short8*)&s_bufA[ag2 * (MB * LDOA) + l15 * LDOA + quad * 8];
        short8 a1 = *(const short8*)&s_bufA[ag2 * (MB * LDOA) + l15 * LDOA + 32 + quad * 8];
        floatx4 acc0 = {}, acc1 = {};
        acc0 = MFMA(a0, w1_200, acc0);
        acc0 = MFMA(a1, w1_201, acc0);
        acc1 = MFMA(a0, w1_210, acc1);
        acc1 = MFMA(a1, w1_211, acc1);
        int col0 = nh2 * 32 + l15;
        #pragma unroll
        for (int rg = 0; rg < 4; rg++) {
            int m = quad * 4 + rg;
            s_oaemb[(m * NA + ag2) * LDC + col0]      = f2bf(leaky(acc0[rg] + b1_20));
            s_oaemb[(m * NA + ag2) * LDC + col0 + 16] = f2bf(leaky(acc1[rg] + b1_21));
        }
    }
    __syncthreads();

    // ---- stage 2: Q (scale folded into Wq) and K; 1 job/wave, named fragments ----
    {
        const u16* Abuf = proj ? s_oaemb : s_oemb;
        u16* dst = proj ? s_bufB : s_bufA;
        int col0 = nh2 * 32 + l15;
        for (int mt = 0; mt < 3; mt++) {
            short8 xa0 = *(const short8*)&Abuf[(mt * 16 + l15) * LDC + 0  + quad * 8];
            short8 xa1 = *(const short8*)&Abuf[(mt * 16 + l15) * LDC + 32 + quad * 8];
            short8 xa2 = *(const short8*)&Abuf[(mt * 16 + l15) * LDC + 64 + quad * 8];
            short8 xa3 = *(const short8*)&Abuf[(mt * 16 + l15) * LDC + 96 + quad * 8];
            floatx4 acc0 = {}, acc1 = {};
            acc0 = MFMA(xa0, w2_00, acc0); acc0 = MFMA(xa1, w2_01, acc0);
            acc0 = MFMA(xa2, w2_02, acc0); acc0 = MFMA(xa3, w2_03, acc0);
            acc1 = MFMA(xa0, w2_10, acc1); acc1 = MFMA(xa1, w2_11, acc1);
            acc1 = MFMA(xa2, w2_12, acc1); acc1 = MFMA(xa3, w2_13, acc1);
            #pragma unroll
            for (int rg = 0; rg < 4; rg++) {
                int m = mt * 16 + quad * 4 + rg;
                dst[m * LDC + col0]      = f2bf(acc0[rg] + b2_0);
                dst[m * LDC + col0 + 16] = f2bf(acc1[rg] + b2_1);
            }
        }
    }
    __syncthreads();

    // ============ PREFETCH stage-4 weights/biases (drain under stage 3a/3b) ============
    short8 w4_00 = preV[OFF_WC1 / 8 + 0 * 4096 + (wave * 8 + 0) * 64 + lane];
    short8 w4_01 = preV[OFF_WC1 / 8 + 0 * 4096 + (wave * 8 + 1) * 64 + lane];
    short8 w4_02 = preV[OFF_WC1 / 8 + 0 * 4096 + (wave * 8 + 2) * 64 + lane];
    short8 w4_03 = preV[OFF_WC1 / 8 + 0 * 4096 + (wave * 8 + 3) * 64 + lane];
    short8 w4_04 = preV[OFF_WC1 / 8 + 0 * 4096 + (wave * 8 + 4) * 64 + lane];
    short8 w4_05 = preV[OFF_WC1 / 8 + 0 * 4096 + (wave * 8 + 5) * 64 + lane];
    short8 w4_06 = preV[OFF_WC1 / 8 + 0 * 4096 + (wave * 8 + 6) * 64 + lane];
    short8 w4_07 = preV[OFF_WC1 / 8 + 0 * 4096 + (wave * 8 + 7) * 64 + lane];
    short8 w4_10 = preV[OFF_WC1 / 8 + 1 * 4096 + (wave * 8 + 0) * 64 + lane];
    short8 w4_11 = preV[OFF_WC1 / 8 + 1 * 4096 + (wave * 8 + 1) * 64 + lane];
    short8 w4_12 = preV[OFF_WC1 / 8 + 1 * 4096 + (wave * 8 + 2) * 64 + lane];
    short8 w4_13 = preV[OFF_WC1 / 8 + 1 * 4096 + (wave * 8 + 3) * 64 + lane];
    short8 w4_14 = preV[OFF_WC1 / 8 + 1 * 4096 + (wave * 8 + 4) * 64 + lane];
    short8 w4_15 = preV[OFF_WC1 / 8 + 1 * 4096 + (wave * 8 + 5) * 64 + lane];
    short8 w4_16 = preV[OFF_WC1 / 8 + 1 * 4096 + (wave * 8 + 6) * 64 + lane];
    short8 w4_17 = preV[OFF_WC1 / 8 + 1 * 4096 + (wave * 8 + 7) * 64 + lane];
    short8 w4_20 = preV[OFF_WC1 / 8 + 2 * 4096 + (wave * 8 + 0) * 64 + lane];
    short8 w4_21 = preV[OFF_WC1 / 8 + 2 * 4096 + (wave * 8 + 1) * 64 + lane];
    short8 w4_22 = preV[OFF_WC1 / 8 + 2 * 4096 + (wave * 8 + 2) * 64 + lane];
    short8 w4_23 = preV[OFF_WC1 / 8 + 2 * 4096 + (wave * 8 + 3) * 64 + lane];
    short8 w4_24 = preV[OFF_WC1 / 8 + 2 * 4096 + (wave * 8 + 4) * 64 + lane];
    short8 w4_25 = preV[OFF_WC1 / 8 + 2 * 4096 + (wave * 8 + 5) * 64 + lane];
    short8 w4_26 = preV[OFF_WC1 / 8 + 2 * 4096 + (wave * 8 + 6) * 64 + lane];
    short8 w4_27 = preV[OFF_WC1 / 8 + 2 * 4096 + (wave * 8 + 7) * 64 + lane];
    float b4_0 = bc1[0 * HID + wave * 16 + l15];
    float b4_1 = bc1[1 * HID + wave * 16 + l15];
    float b4_2 = bc1[2 * HID + wave * 16 + l15];

    // ---- stage 3a: masked softmax, off-diagonal only; probs stay in registers ----
    float2 prob = make_float2(0.f, 0.f);
    int e3 = 0, h3 = 0, n3 = 0, m30 = 0, m31 = 0;
    const bool attn_thread = (tid < MB * HEADS * NA);
    if (attn_thread) {
        int r = tid;
        e3 = r / (HEADS * NA); r -= e3 * HEADS * NA; h3 = r / NA; n3 = r - h3 * NA;
        m30 = (n3 == 0) ? 1 : 0;
        m31 = (n3 == 2) ? 1 : 2;
        const uint4* qp  = (const uint4*)&s_bufA[(e3 * NA + n3) * LDC + h3 * HD];
        const uint4* kp0 = (const uint4*)&s_bufB[(e3 * NA + m30) * LDC + h3 * HD];
        const uint4* kp1 = (const uint4*)&s_bufB[(e3 * NA + m31) * LDC + h3 * HD];
        float s0 = 0.f, s1 = 0.f;
        #pragma unroll
        for (int c = 0; c < 4; c++) {
            uint4 qw = qp[c], aw = kp0[c], bw = kp1[c];
            u32 qv[4] = {qw.x, qw.y, qw.z, qw.w};
            u32 av[4] = {aw.x, aw.y, aw.z, aw.w};
            u32 bv_[4] = {bw.x, bw.y, bw.z, bw.w};
            #pragma unroll
            for (int j = 0; j < 4; j++) {
                float ql = lo16f(qv[j]), qh = hi16f(qv[j]);
                s0 += ql * lo16f(av[j]) + qh * hi16f(av[j]);
                s1 += ql * lo16f(bv_[j]) + qh * hi16f(bv_[j]);
            }
        }
        float mx = fmaxf(s0, s1);
        float p0 = __expf(s0 - mx), p1 = __expf(s1 - mx);
        float inv = 1.f / (p0 + p1);
        prob = make_float2(p0 * inv, p1 * inv);
    }
    __syncthreads();

    // ---- stage 3b: V = oa_emb @ Wv + bv ; 1 job/wave (nt = wave) ----
    {
        int colv = wave * 16 + l15;
        for (int mt = 0; mt < 3; mt++) {
            short8 xa0 = *(const short8*)&s_oaemb[(mt * 16 + l15) * LDC + 0  + quad * 8];
            short8 xa1 = *(const short8*)&s_oaemb[(mt * 16 + l15) * LDC + 32 + quad * 8];
            short8 xa2 = *(const short8*)&s_oaemb[(mt * 16 + l15) * LDC + 64 + quad * 8];
            short8 xa3 = *(const short8*)&s_oaemb[(mt * 16 + l15) * LDC + 96 + quad * 8];
            floatx4 acc = {};
            acc = MFMA(xa0, w3_0, acc); acc = MFMA(xa1, w3_1, acc);
            acc = MFMA(xa2, w3_2, acc); acc = MFMA(xa3, w3_3, acc);
            #pragma unroll
            for (int rg = 0; rg < 4; rg++) {
                int m = mt * 16 + quad * 4 + rg;
                s_bufA[m * LDC + colv] = f2bf(acc[rg] + b3v);
            }
        }
    }
    __syncthreads();

    // ---- stage 3c: attn_out = probs @ V (probs from registers) ----
    if (attn_thread) {
        const uint4* v0p = (const uint4*)&s_bufA[(e3 * NA + m30) * LDC + h3 * HD];
        const uint4* v1p = (const uint4*)&s_bufA[(e3 * NA + m31) * LDC + h3 * HD];
        uint4* dst = (uint4*)&s_oaemb[(e3 * NA + n3) * LDC + h3 * HD];
        #pragma unroll
        for (int c = 0; c < 4; c++) {
            uint4 aw = v0p[c], bw = v1p[c], ow;
            u32 av[4] = {aw.x, aw.y, aw.z, aw.w};
            u32 bv_[4] = {bw.x, bw.y, bw.z, bw.w};
            u32 ov[4];
            #pragma unroll
            for (int j = 0; j < 4; j++) {
                float lo = prob.x * lo16f(av[j]) + prob.y * lo16f(bv_[j]);
                float hi = prob.x * hi16f(av[j]) + prob.y * hi16f(bv_[j]);
                ov[j] = pk_bf16(lo, hi);
            }
            ow.x = ov[0]; ow.y = ov[1]; ow.z = ov[2]; ow.w = ov[3];
            dst[c] = ow;
        }
    }
    __syncthreads();

    // ============ PREFETCH stage-5 weights/bias (drain under stage 4) ============
    const int w5a = (wave < NA) ? wave : 0;       // clamp keeps loads in-bounds for all waves
    short8 w5_0 = preV[OFF_WC2 / 8 + w5a * 256 + 0 * 64 + lane];
    short8 w5_1 = preV[OFF_WC2 / 8 + w5a * 256 + 1 * 64 + lane];
    short8 w5_2 = preV[OFF_WC2 / 8 + w5a * 256 + 2 * 64 + lane];
    short8 w5_3 = preV[OFF_WC2 / 8 + w5a * 256 + 3 * 64 + lane];
    float b5v = bc2[w5a * ACTD + ((l15 < ACTD) ? l15 : 0)];

    // ---- stage 4: critic layer 1, 3 jobs/wave (agent=j, nt=wave); named fragments ----
    {
        int colc = wave * 16 + l15;
        // agent 0
        {
            floatx4 acc = {};
            short8 a;
            a = *(const short8*)&s_oemb [(l15 * NA + 0) * LDC + 0  + quad * 8]; acc = MFMA(a, w4_00, acc);
            a = *(const short8*)&s_oemb [(l15 * NA + 0) * LDC + 32 + quad * 8]; acc = MFMA(a, w4_01, acc);
            a = *(const short8*)&s_oemb [(l15 * NA + 0) * LDC + 64 + quad * 8]; acc = MFMA(a, w4_02, acc);
            a = *(const short8*)&s_oemb [(l15 * NA + 0) * LDC + 96 + quad * 8]; acc = MFMA(a, w4_03, acc);
            a = *(const short8*)&s_oaemb[(l15 * NA + 0) * LDC + 0  + quad * 8]; acc = MFMA(a, w4_04, acc);
            a = *(const short8*)&s_oaemb[(l15 * NA + 0) * LDC + 32 + quad * 8]; acc = MFMA(a, w4_05, acc);
            a = *(const short8*)&s_oaemb[(l15 * NA + 0) * LDC + 64 + quad * 8]; acc = MFMA(a, w4_06, acc);
            a = *(const short8*)&s_oaemb[(l15 * NA + 0) * LDC + 96 + quad * 8]; acc = MFMA(a, w4_07, acc);
            #pragma unroll
            for (int rg = 0; rg < 4; rg++) {
                int m = quad * 4 + rg;
                s_bufB[(m * NA + 0) * LDC + colc] = f2bf(leaky(acc[rg] + b4_0));
            }
        }
        // agent 1
        {
            floatx4 acc = {};
            short8 a;
            a = *(const short8*)&s_oemb [(l15 * NA + 1) * LDC + 0  + quad * 8]; acc = MFMA(a, w4_10, acc);
            a = *(const short8*)&s_oemb [(l15 * NA + 1) * LDC + 32 + quad * 8]; acc = MFMA(a, w4_11, acc);
            a = *(const short8*)&s_oemb [(l15 * NA + 1) * LDC + 64 + quad * 8]; acc = MFMA(a, w4_12, acc);
            a = *(const short8*)&s_oemb [(l15 * NA + 1) * LDC + 96 + quad * 8]; acc = MFMA(a, w4_13, acc);
            a = *(const short8*)&s_oaemb[(l15 * NA + 1) * LDC + 0  + quad * 8]; acc = MFMA(a, w4_14, acc);
            a = *(const short8*)&s_oaemb[(l15 * NA + 1) * LDC + 32 + quad * 8]; acc = MFMA(a, w4_15, acc);
            a = *(const short8*)&s_oaemb[(l15 * NA + 1) * LDC + 64 + quad * 8]; acc = MFMA(a, w4_16, acc);
            a = *(const short8*)&s_oaemb[(l15 * NA + 1) * LDC + 96 + quad * 8]; acc = MFMA(a, w4_17, acc);
            #pragma unroll
            for (int rg = 0; rg < 4; rg++) {
                int m = quad * 4 + rg;
                s_bufB[(m * NA + 1) * LDC + colc] = f2bf(leaky(acc[rg] + b4_1));
            }
        }
        // agent 2
        {
            floatx4 acc = {};
            short8 a;
            a = *(const short8*)&s_oemb [(l15 * NA + 2) * LDC + 0  + quad * 8]; acc = MFMA(a, w4_20, acc);
            a = *(const short8*)&s_oemb [(l15 * NA + 2) * LDC + 32 + quad * 8]; acc = MFMA(a, w4_21, acc);
            a = *(const short8*)&s_oemb [(l15 * NA + 2) * LDC + 64 + quad * 8]; acc = MFMA(a, w4_22, acc);
            a = *(const short8*)&s_oemb [(l15 * NA + 2) * LDC + 96 + quad * 8]; acc = MFMA(a, w4_23, acc);
            a = *(const short8*)&s_oaemb[(l15 * NA + 2) * LDC + 0  + quad * 8]; acc = MFMA(a, w4_24, acc);
            a = *(const short8*)&s_oaemb[(l15 * NA + 2) * LDC + 32 + quad * 8]; acc = MFMA(a, w4_25, acc);
            a = *(const short8*)&s_oaemb[(l15 * NA + 2) * LDC + 64 + quad * 8]; acc = MFMA(a, w4_26, acc);
            a = *(const short8*)&s_oaemb[(l15 * NA + 2) * LDC + 96 + quad * 8]; acc = MFMA(a, w4_27, acc);
            #pragma unroll
            for (int rg = 0; rg < 4; rg++) {
                int m = quad * 4 + rg;
                s_bufB[(m * NA + 2) * LDC + colc] = f2bf(leaky(acc[rg] + b4_2));
            }
        }
    }
    __syncthreads();

    // ---- stage 5: critic layer 2 -> q_values, f32 out ----
    if (wave < NA) {
        int agent = wave;
        floatx4 acc = {};
        short8 a;
        a = *(const short8*)&s_bufB[(l15 * NA + agent) * LDC + 0  + quad * 8]; acc = MFMA(a, w5_0, acc);
        a = *(const short8*)&s_bufB[(l15 * NA + agent) * LDC + 32 + quad * 8]; acc = MFMA(a, w5_1, acc);
        a = *(const short8*)&s_bufB[(l15 * NA + agent) * LDC + 64 + quad * 8]; acc = MFMA(a, w5_2, acc);
        a = *(const short8*)&s_bufB[(l15 * NA + agent) * LDC + 96 + quad * 8]; acc = MFMA(a, w5_3, acc);
        if (l15 < ACTD) {
            #pragma unroll
            for (int rg = 0; rg < 4; rg++) {
                int m = quad * 4 + rg;
                out[((b0 + m) * NA + agent) * ACTD + l15] = acc[rg] + b5v;
            }
        }
    }
}

extern "C" void kernel_launch(void* const* d_in, const int* in_sizes, int n_in,
                              void* d_out, int out_size, void* d_ws, size_t ws_size,
                              hipStream_t stream) {
    const float* obs = (const float*)d_in[0];
    const float* act = (const float*)d_in[1];
    const float* Wo  = (const float*)d_in[2];
    const float* bo  = (const float*)d_in[3];
    const float* Woa = (const float*)d_in[4];
    const float* boa = (const float*)d_in[5];
    const float* Wq  = (const float*)d_in[6];
    const float* bq  = (const float*)d_in[7];
    const float* Wk  = (const float*)d_in[8];
    const float* bk  = (const float*)d_in[9];
    const float* Wv  = (const float*)d_in[10];
    const float* bv  = (const float*)d_in[11];
    const float* Wc1 = (const float*)d_in[12];
    const float* bc1 = (const float*)d_in[13];
    const float* Wc2 = (const float*)d_in[14];
    const float* bc2 = (const float*)d_in[15];
    u16* pre = (u16*)d_ws;   // needs 380928 B of workspace

    prepack_kernel<<<(PRE_TOTAL + 255) / 256, 256, 0, stream>>>(Wo, Woa, Wq, Wk, Wv, Wc1, Wc2, pre);
    fused_kernel<<<BATCH / MB, NTHREADS, 0, stream>>>(obs, act, bo, boa, bq, bk, bv, bc1, bc2, pre,
                                                      (float*)d_out);
}

// Round 5
// 369.517 us; speedup vs baseline: 2.4287x; 2.3625x over previous
//
#include <hip/hip_runtime.h>
#include <stdint.h>

typedef unsigned short u16;
typedef unsigned int u32;
typedef __attribute__((ext_vector_type(8))) short short8;
typedef __attribute__((ext_vector_type(4))) float floatx4;

#define BATCH   131072
#define NA      3
#define OBS     30
#define ACTD    9
#define HID     128
#define HEADS   4
#define HD      32
#define MB      16
#define ROWS    (MB*NA)     // 48
#define LDC     136         // padded row stride
#define LDOA    72          // oa input tile stride
#define QSCALE  0.17677669529663687f
#define NTHREADS 512

// prepacked-weight offsets in d_ws, u16 units (fragment = 64 lanes x 8 bf16)
#define OFF_WO    0
#define OFF_WOA   12288
#define OFF_WQ    36864
#define OFF_WK    53248
#define OFF_WV    69632
#define OFF_WC1   86016
#define OFF_WC2   184320
#define PRE_TOTAL 190464

#define MFMA(A,B,C) __builtin_amdgcn_mfma_f32_16x16x32_bf16((A),(B),(C),0,0,0)

__device__ __forceinline__ u16 f2bf(float f) {          // round-nearest (ties up)
    union { float f; u32 u; } v; v.f = f;
    return (u16)((v.u + 0x8000u) >> 16);
}
__device__ __forceinline__ u32 pk_bf16(float a, float b) {
    union { float f; u32 u; } x, y; x.f = a; y.f = b;
    return ((x.u + 0x8000u) >> 16) | ((y.u + 0x8000u) & 0xffff0000u);
}
__device__ __forceinline__ float lo16f(u32 w) { union { u32 u; float f; } v; v.u = w << 16; return v.f; }
__device__ __forceinline__ float hi16f(u32 w) { union { u32 u; float f; } v; v.u = w & 0xffff0000u; return v.f; }
__device__ __forceinline__ float leaky(float x) { return x >= 0.f ? x : 0.01f * x; }

// ------------- weight prepack: f32 [k][n] -> bf16 MFMA B-fragment order -------------
__global__ void prepack_kernel(const float* __restrict__ Wo,  const float* __restrict__ Woa,
                               const float* __restrict__ Wq,  const float* __restrict__ Wk,
                               const float* __restrict__ Wv,  const float* __restrict__ Wc1,
                               const float* __restrict__ Wc2, u16* __restrict__ out) {
    int i = blockIdx.x * blockDim.x + threadIdx.x;
    if (i >= PRE_TOTAL) return;
    const float* src; int K, KT, perA, base, Nsrc, Nlim; float scl = 1.f;
    if (i < OFF_WOA)      { src = Wo;  K = 30;  KT = 1; perA = 4096;  base = OFF_WO;  Nsrc = 128; Nlim = 128; }
    else if (i < OFF_WQ)  { src = Woa; K = 39;  KT = 2; perA = 8192;  base = OFF_WOA; Nsrc = 128; Nlim = 128; }
    else if (i < OFF_WK)  { src = Wq;  K = 128; KT = 4; perA = 16384; base = OFF_WQ;  Nsrc = 128; Nlim = 128; scl = QSCALE; }
    else if (i < OFF_WV)  { src = Wk;  K = 128; KT = 4; perA = 16384; base = OFF_WK;  Nsrc = 128; Nlim = 128; }
    else if (i < OFF_WC1) { src = Wv;  K = 128; KT = 4; perA = 16384; base = OFF_WV;  Nsrc = 128; Nlim = 128; }
    else if (i < OFF_WC2) { src = Wc1; K = 256; KT = 8; perA = 32768; base = OFF_WC1; Nsrc = 128; Nlim = 128; }
    else                  { src = Wc2; K = 128; KT = 4; perA = 2048;  base = OFF_WC2; Nsrc = 9;   Nlim = 9;   }
    int j = i - base;
    int agent = j / perA;
    int r = j - agent * perA;
    int e = r & 7, lane = (r >> 3) & 63, fk = r >> 9;
    int kt = fk % KT, nt = fk / KT;
    int n = nt * 16 + (lane & 15);
    int k = kt * 32 + (lane >> 4) * 8 + e;
    u16 v = 0;
    if (k < K && n < Nlim) v = f2bf(src[(agent * K + k) * Nsrc + n] * scl);
    out[i] = v;
}

// ---------------- fused forward: 512 threads (8 waves) ----------------
// __launch_bounds__(512,4): VGPR cap = 512/4 = 128/wave (pool is 512/SIMD), 2 blocks/CU.
// One-barrier-ahead register prefetch in NAMED scalars, peak live-set ~115 VGPR
// (w4 split across 3a-top / 3c-top so the 96-reg critic-weight set never coexists
// with stage-3 working state). sched_barrier(0) pins each prefetch issue point.
__global__ __launch_bounds__(NTHREADS, 4) void fused_kernel(
    const float* __restrict__ obs, const float* __restrict__ act,
    const float* __restrict__ b_o, const float* __restrict__ b_oa,
    const float* __restrict__ bq,  const float* __restrict__ bk_, const float* __restrict__ bv,
    const float* __restrict__ bc1, const float* __restrict__ bc2,
    const u16* __restrict__ pre, float* __restrict__ out)
{
    __shared__ __align__(16) u16 s_mem[4 * ROWS * LDC];        // 52224 B
    u16* s_oemb  = s_mem;                    // o_emb (persistent)
    u16* s_oaemb = s_mem + ROWS * LDC;       // oa_emb -> attn_out
    u16* s_bufA  = s_mem + 2 * ROWS * LDC;   // oa-tile -> Q -> V
    u16* s_bufB  = s_mem + 3 * ROWS * LDC;   // K -> h

    const int tid  = threadIdx.x;
    const int wave = tid >> 6, lane = tid & 63;
    const int l15  = lane & 15, quad = lane >> 4;
    const int b0   = blockIdx.x * MB;
    const short8* preV = (const short8*)pre;

    const int nh2 = wave & 3;                // shared n-tile-pair index for stage-1 jobs & stage 2

    // ============ PREFETCH stage-1 weights/biases (drain under stage 0) ============
    const int ag0 = wave >> 2;
    const int ag2 = (wave + 4) >> 2;
    const int pb0 = OFF_WO / 8 + ag0 * 512;
    const int pb1 = (wave < 4) ? (OFF_WO / 8 + 2 * 512) : (OFF_WOA / 8);
    const int kt1n = (wave < 4) ? 1 : 2;     // job1 KT
    const int pb2 = OFF_WOA / 8 + ag2 * 1024;
    short8 w1_00 = preV[pb0 + (nh2 * 2 + 0) * 64 + lane];
    short8 w1_01 = preV[pb0 + (nh2 * 2 + 1) * 64 + lane];
    short8 w1_100 = preV[pb1 + ((nh2 * 2 + 0) * kt1n + 0) * 64 + lane];
    short8 w1_101 = preV[pb1 + ((nh2 * 2 + 0) * kt1n + 1) * 64 + lane];   // unused if kt1n==1 (valid mem)
    short8 w1_110 = preV[pb1 + ((nh2 * 2 + 1) * kt1n + 0) * 64 + lane];
    short8 w1_111 = preV[pb1 + ((nh2 * 2 + 1) * kt1n + 1) * 64 + lane];
    short8 w1_200 = preV[pb2 + ((nh2 * 2 + 0) * 2 + 0) * 64 + lane];
    short8 w1_201 = preV[pb2 + ((nh2 * 2 + 0) * 2 + 1) * 64 + lane];
    short8 w1_210 = preV[pb2 + ((nh2 * 2 + 1) * 2 + 0) * 64 + lane];
    short8 w1_211 = preV[pb2 + ((nh2 * 2 + 1) * 2 + 1) * 64 + lane];
    const float* bj0 = b_o + ag0 * HID;
    const float* bj1 = (wave < 4) ? (b_o + 2 * HID) : b_oa;
    const float* bj2 = b_oa + ag2 * HID;
    float b1_00 = bj0[(nh2 * 2 + 0) * 16 + l15];
    float b1_01 = bj0[(nh2 * 2 + 1) * 16 + l15];
    float b1_10 = bj1[(nh2 * 2 + 0) * 16 + l15];
    float b1_11 = bj1[(nh2 * 2 + 1) * 16 + l15];
    float b1_20 = bj2[(nh2 * 2 + 0) * 16 + l15];
    float b1_21 = bj2[(nh2 * 2 + 1) * 16 + l15];

    // ============ PREFETCH stage-2 weights/biases (drain under stage 0) ============
    const int proj = wave >> 2;              // w0-3: Q, w4-7: K
    const int pbqk = (proj ? OFF_WK : OFF_WQ) / 8;
    const float* bqk = proj ? bk_ : bq;
    const float bscl = proj ? 1.f : QSCALE;
    short8 w2_00 = preV[pbqk + ((nh2 * 2 + 0) * 4 + 0) * 64 + lane];
    short8 w2_01 = preV[pbqk + ((nh2 * 2 + 0) * 4 + 1) * 64 + lane];
    short8 w2_02 = preV[pbqk + ((nh2 * 2 + 0) * 4 + 2) * 64 + lane];
    short8 w2_03 = preV[pbqk + ((nh2 * 2 + 0) * 4 + 3) * 64 + lane];
    short8 w2_10 = preV[pbqk + ((nh2 * 2 + 1) * 4 + 0) * 64 + lane];
    short8 w2_11 = preV[pbqk + ((nh2 * 2 + 1) * 4 + 1) * 64 + lane];
    short8 w2_12 = preV[pbqk + ((nh2 * 2 + 1) * 4 + 2) * 64 + lane];
    short8 w2_13 = preV[pbqk + ((nh2 * 2 + 1) * 4 + 3) * 64 + lane];
    float b2_0 = bqk[(nh2 * 2 + 0) * 16 + l15] * bscl;
    float b2_1 = bqk[(nh2 * 2 + 1) * 16 + l15] * bscl;
    __builtin_amdgcn_sched_barrier(0);       // pin prefetch issue above stage 0

    // ---- stage 0: stage [obs|act|0] tile as packed u32 writes, layout [agent][MB][LDOA] ----
    for (int g = tid; g < ROWS * 15; g += NTHREADS) {          // obs k=0..29
        int r = g / 15, s = g - r * 15;
        int n = r / MB, bl = r - n * MB;
        const float* src = &obs[((b0 + bl) * NA + n) * OBS + 2 * s];
        *(u32*)&s_bufA[n * (MB * LDOA) + bl * LDOA + 2 * s] = pk_bf16(src[0], src[1]);
    }
    for (int g = tid; g < ROWS * 5; g += NTHREADS) {           // act k=30..38, zero k=39
        int r = g / 5, s = g - r * 5;
        int n = r / MB, bl = r - n * MB;
        const float* src = &act[((b0 + bl) * NA + n) * ACTD + 2 * s];
        float v0 = src[0], v1 = (s < 4) ? src[1] : 0.f;
        *(u32*)&s_bufA[n * (MB * LDOA) + bl * LDOA + 30 + 2 * s] = pk_bf16(v0, v1);
    }
    for (int g = tid; g < ROWS * 3; g += NTHREADS) {           // zero k=40..63 (uint4)
        int r = g / 3, s = g - r * 3;
        int n = r / MB, bl = r - n * MB;
        *(uint4*)&s_bufA[n * (MB * LDOA) + bl * LDOA + 40 + 8 * s] = make_uint4(0, 0, 0, 0);
    }
    __syncthreads();

    // ============ PREFETCH stage-3b (V) weights (drain under stage 1) ============
    short8 w3_0 = preV[OFF_WV / 8 + (wave * 4 + 0) * 64 + lane];
    short8 w3_1 = preV[OFF_WV / 8 + (wave * 4 + 1) * 64 + lane];
    short8 w3_2 = preV[OFF_WV / 8 + (wave * 4 + 2) * 64 + lane];
    short8 w3_3 = preV[OFF_WV / 8 + (wave * 4 + 3) * 64 + lane];
    float b3v = bv[wave * 16 + l15];
    __builtin_amdgcn_sched_barrier(0);

    // ---- stage 1: per-agent embeds, 3 jobs/wave, named fragments ----
    {
        // job0: agent=ag0, KT=1, dst=s_oemb
        short8 a = *(const short8*)&s_bufA[ag0 * (MB * LDOA) + l15 * LDOA + quad * 8];
        floatx4 acc0 = {}, acc1 = {};
        acc0 = MFMA(a, w1_00, acc0);
        acc1 = MFMA(a, w1_01, acc1);
        int col0 = nh2 * 32 + l15;
        #pragma unroll
        for (int rg = 0; rg < 4; rg++) {
            int m = quad * 4 + rg;
            s_oemb[(m * NA + ag0) * LDC + col0]      = f2bf(leaky(acc0[rg] + b1_00));
            s_oemb[(m * NA + ag0) * LDC + col0 + 16] = f2bf(leaky(acc1[rg] + b1_01));
        }
    }
    {
        // job1: wave<4 -> (o_emb, agent2); wave>=4 -> (oa_emb, agent0)
        int ag1 = (wave < 4) ? 2 : 0;
        short8 a0 = *(const short8*)&s_bufA[ag1 * (MB * LDOA) + l15 * LDOA + quad * 8];
        floatx4 acc0 = {}, acc1 = {};
        acc0 = MFMA(a0, w1_100, acc0);
        acc1 = MFMA(a0, w1_110, acc1);
        if (wave >= 4) {                      // wave-uniform branch
            short8 a1 = *(const short8*)&s_bufA[ag1 * (MB * LDOA) + l15 * LDOA + 32 + quad * 8];
            acc0 = MFMA(a1, w1_101, acc0);
            acc1 = MFMA(a1, w1_111, acc1);
        }
        u16* dst = (wave < 4) ? s_oemb : s_oaemb;
        int col0 = nh2 * 32 + l15;
        #pragma unroll
        for (int rg = 0; rg < 4; rg++) {
            int m = quad * 4 + rg;
            dst[(m * NA + ag1) * LDC + col0]      = f2bf(leaky(acc0[rg] + b1_10));
            dst[(m * NA + ag1) * LDC + col0 + 16] = f2bf(leaky(acc1[rg] + b1_11));
        }
    }
    {
        // job2: oa_emb, agent=ag2, KT=2
        short8 a0 = *(const short8*)&s_bufA[ag2 * (MB * LDOA) + l15 * LDOA + quad * 8];
        short8 a1 = *(const short8*)&s_bufA[ag2 * (MB * LDOA) + l15 * LDOA + 32 + quad * 8];
        floatx4 acc0 = {}, acc1 = {};
        acc0 = MFMA(a0, w1_200, acc0);
        acc0 = MFMA(a1, w1_201, acc0);
        acc1 = MFMA(a0, w1_210, acc1);
        acc1 = MFMA(a1, w1_211, acc1);
        int col0 = nh2 * 32 + l15;
        #pragma unroll
        for (int rg = 0; rg < 4; rg++) {
            int m = quad * 4 + rg;
            s_oaemb[(m * NA + ag2) * LDC + col0]      = f2bf(leaky(acc0[rg] + b1_20));
            s_oaemb[(m * NA + ag2) * LDC + col0 + 16] = f2bf(leaky(acc1[rg] + b1_21));
        }
    }
    __syncthreads();

    // ---- stage 2: Q (scale folded into Wq) and K; 1 job/wave, named fragments ----
    {
        const u16* Abuf = proj ? s_oaemb : s_oemb;
        u16* dst = proj ? s_bufB : s_bufA;
        int col0 = nh2 * 32 + l15;
        for (int mt = 0; mt < 3; mt++) {
            short8 xa0 = *(const short8*)&Abuf[(mt * 16 + l15) * LDC + 0  + quad * 8];
            short8 xa1 = *(const short8*)&Abuf[(mt * 16 + l15) * LDC + 32 + quad * 8];
            short8 xa2 = *(const short8*)&Abuf[(mt * 16 + l15) * LDC + 64 + quad * 8];
            short8 xa3 = *(const short8*)&Abuf[(mt * 16 + l15) * LDC + 96 + quad * 8];
            floatx4 acc0 = {}, acc1 = {};
            acc0 = MFMA(xa0, w2_00, acc0); acc0 = MFMA(xa1, w2_01, acc0);
            acc0 = MFMA(xa2, w2_02, acc0); acc0 = MFMA(xa3, w2_03, acc0);
            acc1 = MFMA(xa0, w2_10, acc1); acc1 = MFMA(xa1, w2_11, acc1);
            acc1 = MFMA(xa2, w2_12, acc1); acc1 = MFMA(xa3, w2_13, acc1);
            #pragma unroll
            for (int rg = 0; rg < 4; rg++) {
                int m = mt * 16 + quad * 4 + rg;
                dst[m * LDC + col0]      = f2bf(acc0[rg] + b2_0);
                dst[m * LDC + col0 + 16] = f2bf(acc1[rg] + b2_1);
            }
        }
    }
    __syncthreads();

    // ============ PREFETCH stage-4 weights agents 0,1 + biases (drain under 3a) ============
    short8 w4_00 = preV[OFF_WC1 / 8 + 0 * 4096 + (wave * 8 + 0) * 64 + lane];
    short8 w4_01 = preV[OFF_WC1 / 8 + 0 * 4096 + (wave * 8 + 1) * 64 + lane];
    short8 w4_02 = preV[OFF_WC1 / 8 + 0 * 4096 + (wave * 8 + 2) * 64 + lane];
    short8 w4_03 = preV[OFF_WC1 / 8 + 0 * 4096 + (wave * 8 + 3) * 64 + lane];
    short8 w4_04 = preV[OFF_WC1 / 8 + 0 * 4096 + (wave * 8 + 4) * 64 + lane];
    short8 w4_05 = preV[OFF_WC1 / 8 + 0 * 4096 + (wave * 8 + 5) * 64 + lane];
    short8 w4_06 = preV[OFF_WC1 / 8 + 0 * 4096 + (wave * 8 + 6) * 64 + lane];
    short8 w4_07 = preV[OFF_WC1 / 8 + 0 * 4096 + (wave * 8 + 7) * 64 + lane];
    short8 w4_10 = preV[OFF_WC1 / 8 + 1 * 4096 + (wave * 8 + 0) * 64 + lane];
    short8 w4_11 = preV[OFF_WC1 / 8 + 1 * 4096 + (wave * 8 + 1) * 64 + lane];
    short8 w4_12 = preV[OFF_WC1 / 8 + 1 * 4096 + (wave * 8 + 2) * 64 + lane];
    short8 w4_13 = preV[OFF_WC1 / 8 + 1 * 4096 + (wave * 8 + 3) * 64 + lane];
    short8 w4_14 = preV[OFF_WC1 / 8 + 1 * 4096 + (wave * 8 + 4) * 64 + lane];
    short8 w4_15 = preV[OFF_WC1 / 8 + 1 * 4096 + (wave * 8 + 5) * 64 + lane];
    short8 w4_16 = preV[OFF_WC1 / 8 + 1 * 4096 + (wave * 8 + 6) * 64 + lane];
    short8 w4_17 = preV[OFF_WC1 / 8 + 1 * 4096 + (wave * 8 + 7) * 64 + lane];
    float b4_0 = bc1[0 * HID + wave * 16 + l15];
    float b4_1 = bc1[1 * HID + wave * 16 + l15];
    float b4_2 = bc1[2 * HID + wave * 16 + l15];
    __builtin_amdgcn_sched_barrier(0);

    // ---- stage 3a: masked softmax, off-diagonal only; probs stay in registers ----
    float2 prob = make_float2(0.f, 0.f);
    int e3 = 0, h3 = 0, n3 = 0, m30 = 0, m31 = 0;
    const bool attn_thread = (tid < MB * HEADS * NA);
    if (attn_thread) {
        int r = tid;
        e3 = r / (HEADS * NA); r -= e3 * HEADS * NA; h3 = r / NA; n3 = r - h3 * NA;
        m30 = (n3 == 0) ? 1 : 0;
        m31 = (n3 == 2) ? 1 : 2;
        const uint4* qp  = (const uint4*)&s_bufA[(e3 * NA + n3) * LDC + h3 * HD];
        const uint4* kp0 = (const uint4*)&s_bufB[(e3 * NA + m30) * LDC + h3 * HD];
        const uint4* kp1 = (const uint4*)&s_bufB[(e3 * NA + m31) * LDC + h3 * HD];
        float s0 = 0.f, s1 = 0.f;
        #pragma unroll
        for (int c = 0; c < 4; c++) {
            uint4 qw = qp[c], aw = kp0[c], bw = kp1[c];
            u32 qv[4] = {qw.x, qw.y, qw.z, qw.w};
            u32 av[4] = {aw.x, aw.y, aw.z, aw.w};
            u32 bv_[4] = {bw.x, bw.y, bw.z, bw.w};
            #pragma unroll
            for (int j = 0; j < 4; j++) {
                float ql = lo16f(qv[j]), qh = hi16f(qv[j]);
                s0 += ql * lo16f(av[j]) + qh * hi16f(av[j]);
                s1 += ql * lo16f(bv_[j]) + qh * hi16f(bv_[j]);
            }
        }
        float mx = fmaxf(s0, s1);
        float p0 = __expf(s0 - mx), p1 = __expf(s1 - mx);
        float inv = 1.f / (p0 + p1);
        prob = make_float2(p0 * inv, p1 * inv);
    }
    __syncthreads();

    // ---- stage 3b: V = oa_emb @ Wv + bv ; 1 job/wave (nt = wave) ----
    {
        int colv = wave * 16 + l15;
        for (int mt = 0; mt < 3; mt++) {
            short8 xa0 = *(const short8*)&s_oaemb[(mt * 16 + l15) * LDC + 0  + quad * 8];
            short8 xa1 = *(const short8*)&s_oaemb[(mt * 16 + l15) * LDC + 32 + quad * 8];
            short8 xa2 = *(const short8*)&s_oaemb[(mt * 16 + l15) * LDC + 64 + quad * 8];
            short8 xa3 = *(const short8*)&s_oaemb[(mt * 16 + l15) * LDC + 96 + quad * 8];
            floatx4 acc = {};
            acc = MFMA(xa0, w3_0, acc); acc = MFMA(xa1, w3_1, acc);
            acc = MFMA(xa2, w3_2, acc); acc = MFMA(xa3, w3_3, acc);
            #pragma unroll
            for (int rg = 0; rg < 4; rg++) {
                int m = mt * 16 + quad * 4 + rg;
                s_bufA[m * LDC + colv] = f2bf(acc[rg] + b3v);
            }
        }
    }
    __syncthreads();

    // ============ PREFETCH stage-4 weights agent 2 (drain under 3c) ============
    short8 w4_20 = preV[OFF_WC1 / 8 + 2 * 4096 + (wave * 8 + 0) * 64 + lane];
    short8 w4_21 = preV[OFF_WC1 / 8 + 2 * 4096 + (wave * 8 + 1) * 64 + lane];
    short8 w4_22 = preV[OFF_WC1 / 8 + 2 * 4096 + (wave * 8 + 2) * 64 + lane];
    short8 w4_23 = preV[OFF_WC1 / 8 + 2 * 4096 + (wave * 8 + 3) * 64 + lane];
    short8 w4_24 = preV[OFF_WC1 / 8 + 2 * 4096 + (wave * 8 + 4) * 64 + lane];
    short8 w4_25 = preV[OFF_WC1 / 8 + 2 * 4096 + (wave * 8 + 5) * 64 + lane];
    short8 w4_26 = preV[OFF_WC1 / 8 + 2 * 4096 + (wave * 8 + 6) * 64 + lane];
    short8 w4_27 = preV[OFF_WC1 / 8 + 2 * 4096 + (wave * 8 + 7) * 64 + lane];
    __builtin_amdgcn_sched_barrier(0);

    // ---- stage 3c: attn_out = probs @ V (probs from registers) ----
    if (attn_thread) {
        const uint4* v0p = (const uint4*)&s_bufA[(e3 * NA + m30) * LDC + h3 * HD];
        const uint4* v1p = (const uint4*)&s_bufA[(e3 * NA + m31) * LDC + h3 * HD];
        uint4* dst = (uint4*)&s_oaemb[(e3 * NA + n3) * LDC + h3 * HD];
        #pragma unroll
        for (int c = 0; c < 4; c++) {
            uint4 aw = v0p[c], bw = v1p[c], ow;
            u32 av[4] = {aw.x, aw.y, aw.z, aw.w};
            u32 bv_[4] = {bw.x, bw.y, bw.z, bw.w};
            u32 ov[4];
            #pragma unroll
            for (int j = 0; j < 4; j++) {
                float lo = prob.x * lo16f(av[j]) + prob.y * lo16f(bv_[j]);
                float hi = prob.x * hi16f(av[j]) + prob.y * hi16f(bv_[j]);
                ov[j] = pk_bf16(lo, hi);
            }
            ow.x = ov[0]; ow.y = ov[1]; ow.z = ov[2]; ow.w = ov[3];
            dst[c] = ow;
        }
    }
    __syncthreads();

    // ---- stage 4: critic layer 1, 3 jobs/wave (agent=j, nt=wave); named fragments ----
    {
        int colc = wave * 16 + l15;
        // agent 0
        {
            floatx4 acc = {};
            short8 a;
            a = *(const short8*)&s_oemb [(l15 * NA + 0) * LDC + 0  + quad * 8]; acc = MFMA(a, w4_00, acc);
            a = *(const short8*)&s_oemb [(l15 * NA + 0) * LDC + 32 + quad * 8]; acc = MFMA(a, w4_01, acc);
            a = *(const short8*)&s_oemb [(l15 * NA + 0) * LDC + 64 + quad * 8]; acc = MFMA(a, w4_02, acc);
            a = *(const short8*)&s_oemb [(l15 * NA + 0) * LDC + 96 + quad * 8]; acc = MFMA(a, w4_03, acc);
            a = *(const short8*)&s_oaemb[(l15 * NA + 0) * LDC + 0  + quad * 8]; acc = MFMA(a, w4_04, acc);
            a = *(const short8*)&s_oaemb[(l15 * NA + 0) * LDC + 32 + quad * 8]; acc = MFMA(a, w4_05, acc);
            a = *(const short8*)&s_oaemb[(l15 * NA + 0) * LDC + 64 + quad * 8]; acc = MFMA(a, w4_06, acc);
            a = *(const short8*)&s_oaemb[(l15 * NA + 0) * LDC + 96 + quad * 8]; acc = MFMA(a, w4_07, acc);
            #pragma unroll
            for (int rg = 0; rg < 4; rg++) {
                int m = quad * 4 + rg;
                s_bufB[(m * NA + 0) * LDC + colc] = f2bf(leaky(acc[rg] + b4_0));
            }
        }
        // agent 1
        {
            floatx4 acc = {};
            short8 a;
            a = *(const short8*)&s_oemb [(l15 * NA + 1) * LDC + 0  + quad * 8]; acc = MFMA(a, w4_10, acc);
            a = *(const short8*)&s_oemb [(l15 * NA + 1) * LDC + 32 + quad * 8]; acc = MFMA(a, w4_11, acc);
            a = *(const short8*)&s_oemb [(l15 * NA + 1) * LDC + 64 + quad * 8]; acc = MFMA(a, w4_12, acc);
            a = *(const short8*)&s_oemb [(l15 * NA + 1) * LDC + 96 + quad * 8]; acc = MFMA(a, w4_13, acc);
            a = *(const short8*)&s_oaemb[(l15 * NA + 1) * LDC + 0  + quad * 8]; acc = MFMA(a, w4_14, acc);
            a = *(const short8*)&s_oaemb[(l15 * NA + 1) * LDC + 32 + quad * 8]; acc = MFMA(a, w4_15, acc);
            a = *(const short8*)&s_oaemb[(l15 * NA + 1) * LDC + 64 + quad * 8]; acc = MFMA(a, w4_16, acc);
            a = *(const short8*)&s_oaemb[(l15 * NA + 1) * LDC + 96 + quad * 8]; acc = MFMA(a, w4_17, acc);
            #pragma unroll
            for (int rg = 0; rg < 4; rg++) {
                int m = quad * 4 + rg;
                s_bufB[(m * NA + 1) * LDC + colc] = f2bf(leaky(acc[rg] + b4_1));
            }
        }
        // agent 2
        {
            floatx4 acc = {};
            short8 a;
            a = *(const short8*)&s_oemb [(l15 * NA + 2) * LDC + 0  + quad * 8]; acc = MFMA(a, w4_20, acc);
            a = *(const short8*)&s_oemb [(l15 * NA + 2) * LDC + 32 + quad * 8]; acc = MFMA(a, w4_21, acc);
            a = *(const short8*)&s_oemb [(l15 * NA + 2) * LDC + 64 + quad * 8]; acc = MFMA(a, w4_22, acc);
            a = *(const short8*)&s_oemb [(l15 * NA + 2) * LDC + 96 + quad * 8]; acc = MFMA(a, w4_23, acc);
            a = *(const short8*)&s_oaemb[(l15 * NA + 2) * LDC + 0  + quad * 8]; acc = MFMA(a, w4_24, acc);
            a = *(const short8*)&s_oaemb[(l15 * NA + 2) * LDC + 32 + quad * 8]; acc = MFMA(a, w4_25, acc);
            a = *(const short8*)&s_oaemb[(l15 * NA + 2) * LDC + 64 + quad * 8]; acc = MFMA(a, w4_26, acc);
            a = *(const short8*)&s_oaemb[(l15 * NA + 2) * LDC + 96 + quad * 8]; acc = MFMA(a, w4_27, acc);
            #pragma unroll
            for (int rg = 0; rg < 4; rg++) {
                int m = quad * 4 + rg;
                s_bufB[(m * NA + 2) * LDC + colc] = f2bf(leaky(acc[rg] + b4_2));
            }
        }
    }
    __syncthreads();

    // ---- stage 5: critic layer 2 -> q_values, f32 out (weights loaded in place; small) ----
    if (wave < NA) {
        int agent = wave;
        short8 w5_0 = preV[OFF_WC2 / 8 + agent * 256 + 0 * 64 + lane];
        short8 w5_1 = preV[OFF_WC2 / 8 + agent * 256 + 1 * 64 + lane];
        short8 w5_2 = preV[OFF_WC2 / 8 + agent * 256 + 2 * 64 + lane];
        short8 w5_3 = preV[OFF_WC2 / 8 + agent * 256 + 3 * 64 + lane];
        floatx4 acc = {};
        short8 a;
        a = *(const short8*)&s_bufB[(l15 * NA + agent) * LDC + 0  + quad * 8]; acc = MFMA(a, w5_0, acc);
        a = *(const short8*)&s_bufB[(l15 * NA + agent) * LDC + 32 + quad * 8]; acc = MFMA(a, w5_1, acc);
        a = *(const short8*)&s_bufB[(l15 * NA + agent) * LDC + 64 + quad * 8]; acc = MFMA(a, w5_2, acc);
        a = *(const short8*)&s_bufB[(l15 * NA + agent) * LDC + 96 + quad * 8]; acc = MFMA(a, w5_3, acc);
        if (l15 < ACTD) {
            float b5v = bc2[agent * ACTD + l15];
            #pragma unroll
            for (int rg = 0; rg < 4; rg++) {
                int m = quad * 4 + rg;
                out[((b0 + m) * NA + agent) * ACTD + l15] = acc[rg] + b5v;
            }
        }
    }
}

extern "C" void kernel_launch(void* const* d_in, const int* in_sizes, int n_in,
                              void* d_out, int out_size, void* d_ws, size_t ws_size,
                              hipStream_t stream) {
    const float* obs = (const float*)d_in[0];
    const float* act = (const float*)d_in[1];
    const float* Wo  = (const float*)d_in[2];
    const float* bo  = (const float*)d_in[3];
    const float* Woa = (const float*)d_in[4];
    const float* boa = (const float*)d_in[5];
    const float* Wq  = (const float*)d_in[6];
    const float* bq  = (const float*)d_in[7];
    const float* Wk  = (const float*)d_in[8];
    const float* bk  = (const float*)d_in[9];
    const float* Wv  = (const float*)d_in[10];
    const float* bv  = (const float*)d_in[11];
    const float* Wc1 = (const float*)d_in[12];
    const float* bc1 = (const float*)d_in[13];
    const float* Wc2 = (const float*)d_in[14];
    const float* bc2 = (const float*)d_in[15];
    u16* pre = (u16*)d_ws;   // needs 380928 B of workspace

    prepack_kernel<<<(PRE_TOTAL + 255) / 256, 256, 0, stream>>>(Wo, Woa, Wq, Wk, Wv, Wc1, Wc2, pre);
    fused_kernel<<<BATCH / MB, NTHREADS, 0, stream>>>(obs, act, bo, boa, bq, bk, bv, bc1, bc2, pre,
                                                      (float*)d_out);
}

// Round 6
// 264.007 us; speedup vs baseline: 3.3993x; 1.3997x over previous
//
#include <hip/hip_runtime.h>
#include <stdint.h>

typedef unsigned short u16;
typedef unsigned int u32;
typedef __attribute__((ext_vector_type(8))) short short8;
typedef __attribute__((ext_vector_type(4))) float floatx4;

#define BATCH   131072
#define NA      3
#define OBS     30
#define ACTD    9
#define HID     128
#define HEADS   4
#define HD      32
#define MB      16
#define ROWS    (MB*NA)     // 48
#define LDC     136         // padded row stride
#define LDOA    72          // oa input tile stride
#define QSCALE  0.17677669529663687f
#define NTHREADS 512

// prepacked-weight offsets in d_ws, u16 units (fragment = 64 lanes x 8 bf16)
#define OFF_WO    0
#define OFF_WOA   12288
#define OFF_WQ    36864
#define OFF_WK    53248
#define OFF_WV    69632
#define OFF_WC1   86016
#define OFF_WC2   184320
#define PRE_TOTAL 190464

#define MFMA(A,B,C) __builtin_amdgcn_mfma_f32_16x16x32_bf16((A),(B),(C),0,0,0)

__device__ __forceinline__ u16 f2bf(float f) {          // round-nearest (ties up)
    union { float f; u32 u; } v; v.f = f;
    return (u16)((v.u + 0x8000u) >> 16);
}
__device__ __forceinline__ u32 pk_bf16(float a, float b) {
    union { float f; u32 u; } x, y; x.f = a; y.f = b;
    return ((x.u + 0x8000u) >> 16) | ((y.u + 0x8000u) & 0xffff0000u);
}
__device__ __forceinline__ float lo16f(u32 w) { union { u32 u; float f; } v; v.u = w << 16; return v.f; }
__device__ __forceinline__ float hi16f(u32 w) { union { u32 u; float f; } v; v.u = w & 0xffff0000u; return v.f; }
__device__ __forceinline__ float leaky(float x) { return x >= 0.f ? x : 0.01f * x; }

// ------------- weight prepack: f32 [k][n] -> bf16 MFMA B-fragment order -------------
__global__ void prepack_kernel(const float* __restrict__ Wo,  const float* __restrict__ Woa,
                               const float* __restrict__ Wq,  const float* __restrict__ Wk,
                               const float* __restrict__ Wv,  const float* __restrict__ Wc1,
                               const float* __restrict__ Wc2, u16* __restrict__ out) {
    int i = blockIdx.x * blockDim.x + threadIdx.x;
    if (i >= PRE_TOTAL) return;
    const float* src; int K, KT, perA, base, Nsrc, Nlim; float scl = 1.f;
    if (i < OFF_WOA)      { src = Wo;  K = 30;  KT = 1; perA = 4096;  base = OFF_WO;  Nsrc = 128; Nlim = 128; }
    else if (i < OFF_WQ)  { src = Woa; K = 39;  KT = 2; perA = 8192;  base = OFF_WOA; Nsrc = 128; Nlim = 128; }
    else if (i < OFF_WK)  { src = Wq;  K = 128; KT = 4; perA = 16384; base = OFF_WQ;  Nsrc = 128; Nlim = 128; scl = QSCALE; }
    else if (i < OFF_WV)  { src = Wk;  K = 128; KT = 4; perA = 16384; base = OFF_WK;  Nsrc = 128; Nlim = 128; }
    else if (i < OFF_WC1) { src = Wv;  K = 128; KT = 4; perA = 16384; base = OFF_WV;  Nsrc = 128; Nlim = 128; }
    else if (i < OFF_WC2) { src = Wc1; K = 256; KT = 8; perA = 32768; base = OFF_WC1; Nsrc = 128; Nlim = 128; }
    else                  { src = Wc2; K = 128; KT = 4; perA = 2048;  base = OFF_WC2; Nsrc = 9;   Nlim = 9;   }
    int j = i - base;
    int agent = j / perA;
    int r = j - agent * perA;
    int e = r & 7, lane = (r >> 3) & 63, fk = r >> 9;
    int kt = fk % KT, nt = fk / KT;
    int n = nt * 16 + (lane & 15);
    int k = kt * 32 + (lane >> 4) * 8 + e;
    u16 v = 0;
    if (k < K && n < Nlim) v = f2bf(src[(agent * K + k) * Nsrc + n] * scl);
    out[i] = v;
}

// ---------------- fused forward: 512 threads (8 waves), 3 blocks/CU -> 24 waves/CU ----------------
// WITHIN-STAGE batched fragment loads: each stage opens with all its weight-fragment
// loads as named scalars (short live ranges -> no spill, stays under the 85-VGPR cap
// of (512,6)), giving each wave 8-10 loads in flight instead of 2-3. No cross-barrier
// register carry (rounds 3-5 showed the allocator spills those to scratch).
__global__ __launch_bounds__(NTHREADS, 6) void fused_kernel(
    const float* __restrict__ obs, const float* __restrict__ act,
    const float* __restrict__ b_o, const float* __restrict__ b_oa,
    const float* __restrict__ bq,  const float* __restrict__ bk_, const float* __restrict__ bv,
    const float* __restrict__ bc1, const float* __restrict__ bc2,
    const u16* __restrict__ pre, float* __restrict__ out)
{
    __shared__ __align__(16) u16 s_mem[4 * ROWS * LDC];        // 52224 B -> 3 blk/CU
    u16* s_oemb  = s_mem;                    // o_emb (persistent)
    u16* s_oaemb = s_mem + ROWS * LDC;       // oa_emb -> attn_out
    u16* s_bufA  = s_mem + 2 * ROWS * LDC;   // oa-tile -> Q -> V
    u16* s_bufB  = s_mem + 3 * ROWS * LDC;   // K -> h

    const int tid  = threadIdx.x;
    const int wave = tid >> 6, lane = tid & 63;
    const int l15  = lane & 15, quad = lane >> 4;
    const int b0   = blockIdx.x * MB;
    const short8* preV = (const short8*)pre;

    const int nh2 = wave & 3;                // shared n-tile-pair index for stage-1 jobs & stage 2
    const int ag0 = wave >> 2;
    const int ag2 = (wave + 4) >> 2;
    const int pb0 = OFF_WO / 8 + ag0 * 512;
    const int pb1 = (wave < 4) ? (OFF_WO / 8 + 2 * 512) : (OFF_WOA / 8);
    const int kt1n = (wave < 4) ? 1 : 2;     // job1 KT
    const int pb2 = OFF_WOA / 8 + ag2 * 1024;
    const int proj = wave >> 2;              // w0-3: Q, w4-7: K

    // ---- stage 0: stage [obs|act|0] tile as packed u32 writes, layout [agent][MB][LDOA] ----
    for (int g = tid; g < ROWS * 15; g += NTHREADS) {          // obs k=0..29
        int r = g / 15, s = g - r * 15;
        int n = r / MB, bl = r - n * MB;
        const float* src = &obs[((b0 + bl) * NA + n) * OBS + 2 * s];
        *(u32*)&s_bufA[n * (MB * LDOA) + bl * LDOA + 2 * s] = pk_bf16(src[0], src[1]);
    }
    for (int g = tid; g < ROWS * 5; g += NTHREADS) {           // act k=30..38, zero k=39
        int r = g / 5, s = g - r * 5;
        int n = r / MB, bl = r - n * MB;
        const float* src = &act[((b0 + bl) * NA + n) * ACTD + 2 * s];
        float v0 = src[0], v1 = (s < 4) ? src[1] : 0.f;
        *(u32*)&s_bufA[n * (MB * LDOA) + bl * LDOA + 30 + 2 * s] = pk_bf16(v0, v1);
    }
    for (int g = tid; g < ROWS * 3; g += NTHREADS) {           // zero k=40..63 (uint4)
        int r = g / 3, s = g - r * 3;
        int n = r / MB, bl = r - n * MB;
        *(uint4*)&s_bufA[n * (MB * LDOA) + bl * LDOA + 40 + 8 * s] = make_uint4(0, 0, 0, 0);
    }
    __syncthreads();

    // ---- stage 1: batched weight loads (10 frags, issued together), then 3 jobs/wave ----
    {
        short8 w1_00 = preV[pb0 + (nh2 * 2 + 0) * 64 + lane];
        short8 w1_01 = preV[pb0 + (nh2 * 2 + 1) * 64 + lane];
        short8 w1_100 = preV[pb1 + ((nh2 * 2 + 0) * kt1n + 0) * 64 + lane];
        short8 w1_101 = preV[pb1 + ((nh2 * 2 + 0) * kt1n + 1) * 64 + lane];   // unused if kt1n==1 (valid mem)
        short8 w1_110 = preV[pb1 + ((nh2 * 2 + 1) * kt1n + 0) * 64 + lane];
        short8 w1_111 = preV[pb1 + ((nh2 * 2 + 1) * kt1n + 1) * 64 + lane];
        short8 w1_200 = preV[pb2 + ((nh2 * 2 + 0) * 2 + 0) * 64 + lane];
        short8 w1_201 = preV[pb2 + ((nh2 * 2 + 0) * 2 + 1) * 64 + lane];
        short8 w1_210 = preV[pb2 + ((nh2 * 2 + 1) * 2 + 0) * 64 + lane];
        short8 w1_211 = preV[pb2 + ((nh2 * 2 + 1) * 2 + 1) * 64 + lane];
        const float* bj0 = b_o + ag0 * HID;
        const float* bj1 = (wave < 4) ? (b_o + 2 * HID) : b_oa;
        const float* bj2 = b_oa + ag2 * HID;
        float b1_00 = bj0[(nh2 * 2 + 0) * 16 + l15];
        float b1_01 = bj0[(nh2 * 2 + 1) * 16 + l15];
        float b1_10 = bj1[(nh2 * 2 + 0) * 16 + l15];
        float b1_11 = bj1[(nh2 * 2 + 1) * 16 + l15];
        float b1_20 = bj2[(nh2 * 2 + 0) * 16 + l15];
        float b1_21 = bj2[(nh2 * 2 + 1) * 16 + l15];
        int col0 = nh2 * 32 + l15;
        {
            // job0: agent=ag0, KT=1, dst=s_oemb
            short8 a = *(const short8*)&s_bufA[ag0 * (MB * LDOA) + l15 * LDOA + quad * 8];
            floatx4 acc0 = {}, acc1 = {};
            acc0 = MFMA(a, w1_00, acc0);
            acc1 = MFMA(a, w1_01, acc1);
            #pragma unroll
            for (int rg = 0; rg < 4; rg++) {
                int m = quad * 4 + rg;
                s_oemb[(m * NA + ag0) * LDC + col0]      = f2bf(leaky(acc0[rg] + b1_00));
                s_oemb[(m * NA + ag0) * LDC + col0 + 16] = f2bf(leaky(acc1[rg] + b1_01));
            }
        }
        {
            // job1: wave<4 -> (o_emb, agent2); wave>=4 -> (oa_emb, agent0)
            int ag1 = (wave < 4) ? 2 : 0;
            short8 a0 = *(const short8*)&s_bufA[ag1 * (MB * LDOA) + l15 * LDOA + quad * 8];
            floatx4 acc0 = {}, acc1 = {};
            acc0 = MFMA(a0, w1_100, acc0);
            acc1 = MFMA(a0, w1_110, acc1);
            if (wave >= 4) {                      // wave-uniform branch
                short8 a1 = *(const short8*)&s_bufA[ag1 * (MB * LDOA) + l15 * LDOA + 32 + quad * 8];
                acc0 = MFMA(a1, w1_101, acc0);
                acc1 = MFMA(a1, w1_111, acc1);
            }
            u16* dst = (wave < 4) ? s_oemb : s_oaemb;
            #pragma unroll
            for (int rg = 0; rg < 4; rg++) {
                int m = quad * 4 + rg;
                dst[(m * NA + ag1) * LDC + col0]      = f2bf(leaky(acc0[rg] + b1_10));
                dst[(m * NA + ag1) * LDC + col0 + 16] = f2bf(leaky(acc1[rg] + b1_11));
            }
        }
        {
            // job2: oa_emb, agent=ag2, KT=2
            short8 a0 = *(const short8*)&s_bufA[ag2 * (MB * LDOA) + l15 * LDOA + quad * 8];
            short8 a1 = *(const short8*)&s_bufA[ag2 * (MB * LDOA) + l15 * LDOA + 32 + quad * 8];
            floatx4 acc0 = {}, acc1 = {};
            acc0 = MFMA(a0, w1_200, acc0);
            acc0 = MFMA(a1, w1_201, acc0);
            acc1 = MFMA(a0, w1_210, acc1);
            acc1 = MFMA(a1, w1_211, acc1);
            #pragma unroll
            for (int rg = 0; rg < 4; rg++) {
                int m = quad * 4 + rg;
                s_oaemb[(m * NA + ag2) * LDC + col0]      = f2bf(leaky(acc0[rg] + b1_20));
                s_oaemb[(m * NA + ag2) * LDC + col0 + 16] = f2bf(leaky(acc1[rg] + b1_21));
            }
        }
    }
    __syncthreads();

    // ---- stage 2: batched loads (8 frags), then Q (scale folded into Wq) and K ----
    {
        const int pbqk = (proj ? OFF_WK : OFF_WQ) / 8;
        const float* bqk = proj ? bk_ : bq;
        const float bscl = proj ? 1.f : QSCALE;
        short8 w2_00 = preV[pbqk + ((nh2 * 2 + 0) * 4 + 0) * 64 + lane];
        short8 w2_01 = preV[pbqk + ((nh2 * 2 + 0) * 4 + 1) * 64 + lane];
        short8 w2_02 = preV[pbqk + ((nh2 * 2 + 0) * 4 + 2) * 64 + lane];
        short8 w2_03 = preV[pbqk + ((nh2 * 2 + 0) * 4 + 3) * 64 + lane];
        short8 w2_10 = preV[pbqk + ((nh2 * 2 + 1) * 4 + 0) * 64 + lane];
        short8 w2_11 = preV[pbqk + ((nh2 * 2 + 1) * 4 + 1) * 64 + lane];
        short8 w2_12 = preV[pbqk + ((nh2 * 2 + 1) * 4 + 2) * 64 + lane];
        short8 w2_13 = preV[pbqk + ((nh2 * 2 + 1) * 4 + 3) * 64 + lane];
        float b2_0 = bqk[(nh2 * 2 + 0) * 16 + l15] * bscl;
        float b2_1 = bqk[(nh2 * 2 + 1) * 16 + l15] * bscl;
        const u16* Abuf = proj ? s_oaemb : s_oemb;
        u16* dst = proj ? s_bufB : s_bufA;
        int col0 = nh2 * 32 + l15;
        for (int mt = 0; mt < 3; mt++) {
            short8 xa0 = *(const short8*)&Abuf[(mt * 16 + l15) * LDC + 0  + quad * 8];
            short8 xa1 = *(const short8*)&Abuf[(mt * 16 + l15) * LDC + 32 + quad * 8];
            short8 xa2 = *(const short8*)&Abuf[(mt * 16 + l15) * LDC + 64 + quad * 8];
            short8 xa3 = *(const short8*)&Abuf[(mt * 16 + l15) * LDC + 96 + quad * 8];
            floatx4 acc0 = {}, acc1 = {};
            acc0 = MFMA(xa0, w2_00, acc0); acc0 = MFMA(xa1, w2_01, acc0);
            acc0 = MFMA(xa2, w2_02, acc0); acc0 = MFMA(xa3, w2_03, acc0);
            acc1 = MFMA(xa0, w2_10, acc1); acc1 = MFMA(xa1, w2_11, acc1);
            acc1 = MFMA(xa2, w2_12, acc1); acc1 = MFMA(xa3, w2_13, acc1);
            #pragma unroll
            for (int rg = 0; rg < 4; rg++) {
                int m = mt * 16 + quad * 4 + rg;
                dst[m * LDC + col0]      = f2bf(acc0[rg] + b2_0);
                dst[m * LDC + col0 + 16] = f2bf(acc1[rg] + b2_1);
            }
        }
    }
    __syncthreads();

    // ---- stage 3a: masked softmax, off-diagonal only; probs stay in registers ----
    float2 prob = make_float2(0.f, 0.f);
    int e3 = 0, h3 = 0, n3 = 0, m30 = 0, m31 = 0;
    const bool attn_thread = (tid < MB * HEADS * NA);
    if (attn_thread) {
        int r = tid;
        e3 = r / (HEADS * NA); r -= e3 * HEADS * NA; h3 = r / NA; n3 = r - h3 * NA;
        m30 = (n3 == 0) ? 1 : 0;
        m31 = (n3 == 2) ? 1 : 2;
        const uint4* qp  = (const uint4*)&s_bufA[(e3 * NA + n3) * LDC + h3 * HD];
        const uint4* kp0 = (const uint4*)&s_bufB[(e3 * NA + m30) * LDC + h3 * HD];
        const uint4* kp1 = (const uint4*)&s_bufB[(e3 * NA + m31) * LDC + h3 * HD];
        float s0 = 0.f, s1 = 0.f;
        #pragma unroll
        for (int c = 0; c < 4; c++) {
            uint4 qw = qp[c], aw = kp0[c], bw = kp1[c];
            u32 qv[4] = {qw.x, qw.y, qw.z, qw.w};
            u32 av[4] = {aw.x, aw.y, aw.z, aw.w};
            u32 bv_[4] = {bw.x, bw.y, bw.z, bw.w};
            #pragma unroll
            for (int j = 0; j < 4; j++) {
                float ql = lo16f(qv[j]), qh = hi16f(qv[j]);
                s0 += ql * lo16f(av[j]) + qh * hi16f(av[j]);
                s1 += ql * lo16f(bv_[j]) + qh * hi16f(bv_[j]);
            }
        }
        float mx = fmaxf(s0, s1);
        float p0 = __expf(s0 - mx), p1 = __expf(s1 - mx);
        float inv = 1.f / (p0 + p1);
        prob = make_float2(p0 * inv, p1 * inv);
    }
    __syncthreads();

    // ---- stage 3b: batched loads (4 frags), then V = oa_emb @ Wv + bv ----
    {
        short8 w3_0 = preV[OFF_WV / 8 + (wave * 4 + 0) * 64 + lane];
        short8 w3_1 = preV[OFF_WV / 8 + (wave * 4 + 1) * 64 + lane];
        short8 w3_2 = preV[OFF_WV / 8 + (wave * 4 + 2) * 64 + lane];
        short8 w3_3 = preV[OFF_WV / 8 + (wave * 4 + 3) * 64 + lane];
        float b3v = bv[wave * 16 + l15];
        int colv = wave * 16 + l15;
        for (int mt = 0; mt < 3; mt++) {
            short8 xa0 = *(const short8*)&s_oaemb[(mt * 16 + l15) * LDC + 0  + quad * 8];
            short8 xa1 = *(const short8*)&s_oaemb[(mt * 16 + l15) * LDC + 32 + quad * 8];
            short8 xa2 = *(const short8*)&s_oaemb[(mt * 16 + l15) * LDC + 64 + quad * 8];
            short8 xa3 = *(const short8*)&s_oaemb[(mt * 16 + l15) * LDC + 96 + quad * 8];
            floatx4 acc = {};
            acc = MFMA(xa0, w3_0, acc); acc = MFMA(xa1, w3_1, acc);
            acc = MFMA(xa2, w3_2, acc); acc = MFMA(xa3, w3_3, acc);
            #pragma unroll
            for (int rg = 0; rg < 4; rg++) {
                int m = mt * 16 + quad * 4 + rg;
                s_bufA[m * LDC + colv] = f2bf(acc[rg] + b3v);
            }
        }
    }
    __syncthreads();

    // ---- stage 3c: attn_out = probs @ V (probs from registers) ----
    if (attn_thread) {
        const uint4* v0p = (const uint4*)&s_bufA[(e3 * NA + m30) * LDC + h3 * HD];
        const uint4* v1p = (const uint4*)&s_bufA[(e3 * NA + m31) * LDC + h3 * HD];
        uint4* dst = (uint4*)&s_oaemb[(e3 * NA + n3) * LDC + h3 * HD];
        #pragma unroll
        for (int c = 0; c < 4; c++) {
            uint4 aw = v0p[c], bw = v1p[c], ow;
            u32 av[4] = {aw.x, aw.y, aw.z, aw.w};
            u32 bv_[4] = {bw.x, bw.y, bw.z, bw.w};
            u32 ov[4];
            #pragma unroll
            for (int j = 0; j < 4; j++) {
                float lo = prob.x * lo16f(av[j]) + prob.y * lo16f(bv_[j]);
                float hi = prob.x * hi16f(av[j]) + prob.y * hi16f(bv_[j]);
                ov[j] = pk_bf16(lo, hi);
            }
            ow.x = ov[0]; ow.y = ov[1]; ow.z = ov[2]; ow.w = ov[3];
            dst[c] = ow;
        }
    }
    __syncthreads();

    // ---- stage 4: critic layer 1, 3 jobs/wave; per-agent batches of 8 frags ----
    {
        int colc = wave * 16 + l15;
        float b4_0 = bc1[0 * HID + wave * 16 + l15];
        float b4_1 = bc1[1 * HID + wave * 16 + l15];
        float b4_2 = bc1[2 * HID + wave * 16 + l15];
        // agent 0
        {
            short8 w0 = preV[OFF_WC1 / 8 + 0 * 4096 + (wave * 8 + 0) * 64 + lane];
            short8 w1 = preV[OFF_WC1 / 8 + 0 * 4096 + (wave * 8 + 1) * 64 + lane];
            short8 w2 = preV[OFF_WC1 / 8 + 0 * 4096 + (wave * 8 + 2) * 64 + lane];
            short8 w3 = preV[OFF_WC1 / 8 + 0 * 4096 + (wave * 8 + 3) * 64 + lane];
            short8 w4 = preV[OFF_WC1 / 8 + 0 * 4096 + (wave * 8 + 4) * 64 + lane];
            short8 w5 = preV[OFF_WC1 / 8 + 0 * 4096 + (wave * 8 + 5) * 64 + lane];
            short8 w6 = preV[OFF_WC1 / 8 + 0 * 4096 + (wave * 8 + 6) * 64 + lane];
            short8 w7 = preV[OFF_WC1 / 8 + 0 * 4096 + (wave * 8 + 7) * 64 + lane];
            floatx4 acc = {};
            short8 a;
            a = *(const short8*)&s_oemb [(l15 * NA + 0) * LDC + 0  + quad * 8]; acc = MFMA(a, w0, acc);
            a = *(const short8*)&s_oemb [(l15 * NA + 0) * LDC + 32 + quad * 8]; acc = MFMA(a, w1, acc);
            a = *(const short8*)&s_oemb [(l15 * NA + 0) * LDC + 64 + quad * 8]; acc = MFMA(a, w2, acc);
            a = *(const short8*)&s_oemb [(l15 * NA + 0) * LDC + 96 + quad * 8]; acc = MFMA(a, w3, acc);
            a = *(const short8*)&s_oaemb[(l15 * NA + 0) * LDC + 0  + quad * 8]; acc = MFMA(a, w4, acc);
            a = *(const short8*)&s_oaemb[(l15 * NA + 0) * LDC + 32 + quad * 8]; acc = MFMA(a, w5, acc);
            a = *(const short8*)&s_oaemb[(l15 * NA + 0) * LDC + 64 + quad * 8]; acc = MFMA(a, w6, acc);
            a = *(const short8*)&s_oaemb[(l15 * NA + 0) * LDC + 96 + quad * 8]; acc = MFMA(a, w7, acc);
            #pragma unroll
            for (int rg = 0; rg < 4; rg++) {
                int m = quad * 4 + rg;
                s_bufB[(m * NA + 0) * LDC + colc] = f2bf(leaky(acc[rg] + b4_0));
            }
        }
        // agent 1
        {
            short8 w0 = preV[OFF_WC1 / 8 + 1 * 4096 + (wave * 8 + 0) * 64 + lane];
            short8 w1 = preV[OFF_WC1 / 8 + 1 * 4096 + (wave * 8 + 1) * 64 + lane];
            short8 w2 = preV[OFF_WC1 / 8 + 1 * 4096 + (wave * 8 + 2) * 64 + lane];
            short8 w3 = preV[OFF_WC1 / 8 + 1 * 4096 + (wave * 8 + 3) * 64 + lane];
            short8 w4 = preV[OFF_WC1 / 8 + 1 * 4096 + (wave * 8 + 4) * 64 + lane];
            short8 w5 = preV[OFF_WC1 / 8 + 1 * 4096 + (wave * 8 + 5) * 64 + lane];
            short8 w6 = preV[OFF_WC1 / 8 + 1 * 4096 + (wave * 8 + 6) * 64 + lane];
            short8 w7 = preV[OFF_WC1 / 8 + 1 * 4096 + (wave * 8 + 7) * 64 + lane];
            floatx4 acc = {};
            short8 a;
            a = *(const short8*)&s_oemb [(l15 * NA + 1) * LDC + 0  + quad * 8]; acc = MFMA(a, w0, acc);
            a = *(const short8*)&s_oemb [(l15 * NA + 1) * LDC + 32 + quad * 8]; acc = MFMA(a, w1, acc);
            a = *(const short8*)&s_oemb [(l15 * NA + 1) * LDC + 64 + quad * 8]; acc = MFMA(a, w2, acc);
            a = *(const short8*)&s_oemb [(l15 * NA + 1) * LDC + 96 + quad * 8]; acc = MFMA(a, w3, acc);
            a = *(const short8*)&s_oaemb[(l15 * NA + 1) * LDC + 0  + quad * 8]; acc = MFMA(a, w4, acc);
            a = *(const short8*)&s_oaemb[(l15 * NA + 1) * LDC + 32 + quad * 8]; acc = MFMA(a, w5, acc);
            a = *(const short8*)&s_oaemb[(l15 * NA + 1) * LDC + 64 + quad * 8]; acc = MFMA(a, w6, acc);
            a = *(const short8*)&s_oaemb[(l15 * NA + 1) * LDC + 96 + quad * 8]; acc = MFMA(a, w7, acc);
            #pragma unroll
            for (int rg = 0; rg < 4; rg++) {
                int m = quad * 4 + rg;
                s_bufB[(m * NA + 1) * LDC + colc] = f2bf(leaky(acc[rg] + b4_1));
            }
        }
        // agent 2
        {
            short8 w0 = preV[OFF_WC1 / 8 + 2 * 4096 + (wave * 8 + 0) * 64 + lane];
            short8 w1 = preV[OFF_WC1 / 8 + 2 * 4096 + (wave * 8 + 1) * 64 + lane];
            short8 w2 = preV[OFF_WC1 / 8 + 2 * 4096 + (wave * 8 + 2) * 64 + lane];
            short8 w3 = preV[OFF_WC1 / 8 + 2 * 4096 + (wave * 8 + 3) * 64 + lane];
            short8 w4 = preV[OFF_WC1 / 8 + 2 * 4096 + (wave * 8 + 4) * 64 + lane];
            short8 w5 = preV[OFF_WC1 / 8 + 2 * 4096 + (wave * 8 + 5) * 64 + lane];
            short8 w6 = preV[OFF_WC1 / 8 + 2 * 4096 + (wave * 8 + 6) * 64 + lane];
            short8 w7 = preV[OFF_WC1 / 8 + 2 * 4096 + (wave * 8 + 7) * 64 + lane];
            floatx4 acc = {};
            short8 a;
            a = *(const short8*)&s_oemb [(l15 * NA + 2) * LDC + 0  + quad * 8]; acc = MFMA(a, w0, acc);
            a = *(const short8*)&s_oemb [(l15 * NA + 2) * LDC + 32 + quad * 8]; acc = MFMA(a, w1, acc);
            a = *(const short8*)&s_oemb [(l15 * NA + 2) * LDC + 64 + quad * 8]; acc = MFMA(a, w2, acc);
            a = *(const short8*)&s_oemb [(l15 * NA + 2) * LDC + 96 + quad * 8]; acc = MFMA(a, w3, acc);
            a = *(const short8*)&s_oaemb[(l15 * NA + 2) * LDC + 0  + quad * 8]; acc = MFMA(a, w4, acc);
            a = *(const short8*)&s_oaemb[(l15 * NA + 2) * LDC + 32 + quad * 8]; acc = MFMA(a, w5, acc);
            a = *(const short8*)&s_oaemb[(l15 * NA + 2) * LDC + 64 + quad * 8]; acc = MFMA(a, w6, acc);
            a = *(const short8*)&s_oaemb[(l15 * NA + 2) * LDC + 96 + quad * 8]; acc = MFMA(a, w7, acc);
            #pragma unroll
            for (int rg = 0; rg < 4; rg++) {
                int m = quad * 4 + rg;
                s_bufB[(m * NA + 2) * LDC + colc] = f2bf(leaky(acc[rg] + b4_2));
            }
        }
    }
    __syncthreads();

    // ---- stage 5: critic layer 2 -> q_values, f32 out (batched 4-frag load) ----
    if (wave < NA) {
        int agent = wave;
        short8 w5_0 = preV[OFF_WC2 / 8 + agent * 256 + 0 * 64 + lane];
        short8 w5_1 = preV[OFF_WC2 / 8 + agent * 256 + 1 * 64 + lane];
        short8 w5_2 = preV[OFF_WC2 / 8 + agent * 256 + 2 * 64 + lane];
        short8 w5_3 = preV[OFF_WC2 / 8 + agent * 256 + 3 * 64 + lane];
        floatx4 acc = {};
        short8 a;
        a = *(const short8*)&s_bufB[(l15 * NA + agent) * LDC + 0  + quad * 8]; acc = MFMA(a, w5_0, acc);
        a = *(const short8*)&s_bufB[(l15 * NA + agent) * LDC + 32 + quad * 8]; acc = MFMA(a, w5_1, acc);
        a = *(const short8*)&s_bufB[(l15 * NA + agent) * LDC + 64 + quad * 8]; acc = MFMA(a, w5_2, acc);
        a = *(const short8*)&s_bufB[(l15 * NA + agent) * LDC + 96 + quad * 8]; acc = MFMA(a, w5_3, acc);
        if (l15 < ACTD) {
            float b5v = bc2[agent * ACTD + l15];
            #pragma unroll
            for (int rg = 0; rg < 4; rg++) {
                int m = quad * 4 + rg;
                out[((b0 + m) * NA + agent) * ACTD + l15] = acc[rg] + b5v;
            }
        }
    }
}

extern "C" void kernel_launch(void* const* d_in, const int* in_sizes, int n_in,
                              void* d_out, int out_size, void* d_ws, size_t ws_size,
                              hipStream_t stream) {
    const float* obs = (const float*)d_in[0];
    const float* act = (const float*)d_in[1];
    const float* Wo  = (const float*)d_in[2];
    const float* bo  = (const float*)d_in[3];
    const float* Woa = (const float*)d_in[4];
    const float* boa = (const float*)d_in[5];
    const float* Wq  = (const float*)d_in[6];
    const float* bq  = (const float*)d_in[7];
    const float* Wk  = (const float*)d_in[8];
    const float* bk  = (const float*)d_in[9];
    const float* Wv  = (const float*)d_in[10];
    const float* bv  = (const float*)d_in[11];
    const float* Wc1 = (const float*)d_in[12];
    const float* bc1 = (const float*)d_in[13];
    const float* Wc2 = (const float*)d_in[14];
    const float* bc2 = (const float*)d_in[15];
    u16* pre = (u16*)d_ws;   // needs 380928 B of workspace

    prepack_kernel<<<(PRE_TOTAL + 255) / 256, 256, 0, stream>>>(Wo, Woa, Wq, Wk, Wv, Wc1, Wc2, pre);
    fused_kernel<<<BATCH / MB, NTHREADS, 0, stream>>>(obs, act, bo, boa, bq, bk, bv, bc1, bc2, pre,
                                                      (float*)d_out);
}